// Round 1
// baseline (1529.197 us; speedup 1.0000x reference)
//
#include <hip/hip_runtime.h>
#include <math.h>

#define B_    4
#define T_    1536
#define DIN_  512
#define D_    512
#define K_    2
#define H_    8
#define BAND_ 24
#define DH_   64
#define M_    (B_*T_)      // 6144 rows
#define ALPHA_ 6.0f
#define BETA_  0.5f
#define EPS_   1e-5f

// ---------------- fp32 tiled GEMM: C = A[M,Kd] @ W[Kd,N] + bias (+res) (+gelu)
__global__ __launch_bounds__(256) void gemm_k(
    const float* __restrict__ A, const float* __restrict__ W,
    const float* __restrict__ bias, const float* __restrict__ res,
    float* __restrict__ C, int M, int N, int Kd, int act_gelu) {
  __shared__ float sA[16][64];   // [k][m]
  __shared__ float sB[16][64];   // [k][n]
  const int tid = threadIdx.x;
  const int tx = tid & 15;        // col group
  const int ty = tid >> 4;        // row group
  const int block_n = blockIdx.x * 64;
  const int block_m = blockIdx.y * 64;
  float acc[4][4] = {};

  const int lm  = tid >> 2;          // 0..63  A-row within tile
  const int lk4 = (tid & 3) * 4;     // 0,4,8,12 k offset
  const int lbk = tid >> 4;          // 0..15  B-k within tile
  const int lbn = (tid & 15) * 4;    // 0..60  n offset

  for (int k0 = 0; k0 < Kd; k0 += 16) {
    const float4 a4 = *(const float4*)(A + (size_t)(block_m + lm) * Kd + k0 + lk4);
    const float4 b4 = *(const float4*)(W + (size_t)(k0 + lbk) * N + block_n + lbn);
    __syncthreads();   // previous iteration's LDS reads done
    sA[lk4 + 0][lm] = a4.x; sA[lk4 + 1][lm] = a4.y;
    sA[lk4 + 2][lm] = a4.z; sA[lk4 + 3][lm] = a4.w;
    *(float4*)&sB[lbk][lbn] = b4;
    __syncthreads();
#pragma unroll
    for (int kk = 0; kk < 16; ++kk) {
      float a[4], b[4];
#pragma unroll
      for (int i = 0; i < 4; ++i) a[i] = sA[kk][ty * 4 + i];
#pragma unroll
      for (int j = 0; j < 4; ++j) b[j] = sB[kk][tx * 4 + j];
#pragma unroll
      for (int i = 0; i < 4; ++i)
#pragma unroll
        for (int j = 0; j < 4; ++j)
          acc[i][j] = fmaf(a[i], b[j], acc[i][j]);
    }
  }
#pragma unroll
  for (int i = 0; i < 4; ++i) {
    const int row = block_m + ty * 4 + i;
#pragma unroll
    for (int j = 0; j < 4; ++j) {
      const int col = block_n + tx * 4 + j;
      float v = acc[i][j] + bias[col];
      if (res) v += res[(size_t)row * N + col];
      if (act_gelu) v = 0.5f * v * (1.0f + erff(v * 0.70710678118654752f));
      C[(size_t)row * N + col] = v;
    }
  }
}

// ---------------- block reduction helper (256 threads, D_=512, 2 elems/thread)
__device__ __forceinline__ float block_sum(float s, float* red, int tid) {
  red[tid] = s; __syncthreads();
  for (int o = 128; o > 0; o >>= 1) {
    if (tid < o) red[tid] += red[tid + o];
    __syncthreads();
  }
  float r = red[0];
  __syncthreads();
  return r;
}

// ---------------- plain LayerNorm: out = LN(in) * g + b
__global__ __launch_bounds__(256) void ln_k(const float* __restrict__ in,
                                            const float* __restrict__ g,
                                            const float* __restrict__ b,
                                            float* __restrict__ out) {
  __shared__ float red[256];
  const int row = blockIdx.x, tid = threadIdx.x;
  const float* x = in + (size_t)row * D_;
  const float v0 = x[tid], v1 = x[tid + 256];
  const float mean = block_sum(v0 + v1, red, tid) * (1.0f / D_);
  const float d0 = v0 - mean, d1 = v1 - mean;
  const float var = block_sum(d0 * d0 + d1 * d1, red, tid) * (1.0f / D_);
  const float inv = rsqrtf(var + EPS_);
  out[(size_t)row * D_ + tid]       = d0 * inv * g[tid]       + b[tid];
  out[(size_t)row * D_ + tid + 256] = d1 * inv * g[tid + 256] + b[tid + 256];
}

// ---------------- gate + LN: Xk = X * sigmoid(a*(A-b)); out = LN(Xk)
__global__ __launch_bounds__(256) void scale_ln_k(
    const float* __restrict__ X, const float* __restrict__ Ain, int kk,
    const float* __restrict__ g, const float* __restrict__ b,
    float* __restrict__ Xk, float* __restrict__ out) {
  __shared__ float red[256];
  const int row = blockIdx.x, tid = threadIdx.x;
  const float a = Ain[(size_t)row * K_ + kk];
  const float w = 1.0f / (1.0f + expf(-ALPHA_ * (a - BETA_)));
  const float v0 = X[(size_t)row * D_ + tid] * w;
  const float v1 = X[(size_t)row * D_ + tid + 256] * w;
  Xk[(size_t)row * D_ + tid] = v0;
  Xk[(size_t)row * D_ + tid + 256] = v1;
  const float mean = block_sum(v0 + v1, red, tid) * (1.0f / D_);
  const float d0 = v0 - mean, d1 = v1 - mean;
  const float var = block_sum(d0 * d0 + d1 * d1, red, tid) * (1.0f / D_);
  const float inv = rsqrtf(var + EPS_);
  out[(size_t)row * D_ + tid]       = d0 * inv * g[tid]       + b[tid];
  out[(size_t)row * D_ + tid + 256] = d1 * inv * g[tid + 256] + b[tid + 256];
}

// ---------------- final: out[b, kk*T+t, :] = LN(y + h2 + tag)
__global__ __launch_bounds__(256) void final_ln_k(
    const float* __restrict__ y, const float* __restrict__ h2,
    const float* __restrict__ tags, int kk,
    const float* __restrict__ g, const float* __restrict__ b,
    float* __restrict__ out) {
  __shared__ float red[256];
  const int row = blockIdx.x, tid = threadIdx.x;
  const int bb = row / T_, t = row % T_;
  const size_t orow = (size_t)bb * (K_ * T_) + (size_t)kk * T_ + t;
  const float v0 = y[(size_t)row * D_ + tid] + h2[(size_t)row * D_ + tid]
                 + tags[(size_t)kk * D_ + tid];
  const float v1 = y[(size_t)row * D_ + tid + 256] + h2[(size_t)row * D_ + tid + 256]
                 + tags[(size_t)kk * D_ + tid + 256];
  const float mean = block_sum(v0 + v1, red, tid) * (1.0f / D_);
  const float d0 = v0 - mean, d1 = v1 - mean;
  const float var = block_sum(d0 * d0 + d1 * d1, red, tid) * (1.0f / D_);
  const float inv = rsqrtf(var + EPS_);
  out[orow * D_ + tid]       = d0 * inv * g[tid]       + b[tid];
  out[orow * D_ + tid + 256] = d1 * inv * g[tid + 256] + b[tid + 256];
}

// ---------------- banded attention: one wave per (b,h,t)
__global__ __launch_bounds__(64) void attn_k(
    const float* __restrict__ q, const float* __restrict__ Kp,
    const float* __restrict__ Vp, float* __restrict__ out) {
  const int idx = blockIdx.x;             // (b*H + h)*T + t
  const int t = idx % T_;
  const int h = (idx / T_) % H_;
  const int b = idx / (T_ * H_);
  const int lane = threadIdx.x;
  const int row = b * T_ + t;
  __shared__ float sq[64];
  __shared__ float sp[64];
  sq[lane] = q[(size_t)row * D_ + h * DH_ + lane];
  __syncthreads();

  const int s = t - BAND_ + lane;
  const bool valid = (lane < 2 * BAND_ + 1) && (s >= 0) && (s < T_);
  float score = -1e30f;
  if (valid) {
    const float* kr = Kp + ((size_t)(b * T_ + s) * D_ + h * DH_);
    float sum = 0.0f;
#pragma unroll
    for (int d = 0; d < DH_; ++d) sum = fmaf(sq[d], kr[d], sum);
    score = sum * 0.125f;     // 1/sqrt(64)
  }
  float mx = score;
  for (int o = 32; o > 0; o >>= 1) mx = fmaxf(mx, __shfl_xor(mx, o));
  const float p = valid ? expf(score - mx) : 0.0f;
  float se = p;
  for (int o = 32; o > 0; o >>= 1) se += __shfl_xor(se, o);
  sp[lane] = p / se;
  __syncthreads();

  float acc = 0.0f;
#pragma unroll
  for (int j = 0; j < 2 * BAND_ + 1; ++j) {
    const int ss = t - BAND_ + j;
    if (ss >= 0 && ss < T_)
      acc = fmaf(sp[j], Vp[(size_t)(b * T_ + ss) * D_ + h * DH_ + lane], acc);
  }
  out[(size_t)row * D_ + h * DH_ + lane] = acc;
}

extern "C" void kernel_launch(void* const* d_in, const int* in_sizes, int n_in,
                              void* d_out, int out_size, void* d_ws, size_t ws_size,
                              hipStream_t stream) {
  const float* x_m    = (const float*)d_in[0];
  const float* A      = (const float*)d_in[1];
  const float* W_in   = (const float*)d_in[2];
  const float* b_in   = (const float*)d_in[3];
  const float* ln_q_g = (const float*)d_in[4];
  const float* ln_q_b = (const float*)d_in[5];
  const float* ln_kv_g= (const float*)d_in[6];
  const float* ln_kv_b= (const float*)d_in[7];
  const float* Wq     = (const float*)d_in[8];
  const float* bq     = (const float*)d_in[9];
  const float* Wk     = (const float*)d_in[10];
  const float* bk     = (const float*)d_in[11];
  const float* Wv     = (const float*)d_in[12];
  const float* bv     = (const float*)d_in[13];
  const float* Wo     = (const float*)d_in[14];
  const float* bo     = (const float*)d_in[15];
  const float* ln_f_g = (const float*)d_in[16];
  const float* ln_f_b = (const float*)d_in[17];
  const float* W1     = (const float*)d_in[18];
  const float* b1     = (const float*)d_in[19];
  const float* W2     = (const float*)d_in[20];
  const float* b2     = (const float*)d_in[21];
  const float* ln_s_g = (const float*)d_in[22];
  const float* ln_s_b = (const float*)d_in[23];
  const float* tags   = (const float*)d_in[24];
  float* out = (float*)d_out;

  const size_t MD = (size_t)M_ * D_;
  float* X  = (float*)d_ws;
  float* KV = X  + MD;          // reused as T1 after K/V projections
  float* Kp = KV + MD;
  float* Vp = Kp + MD;
  float* Xk = Vp + MD;
  float* T2 = Xk + MD;
  float* H1 = T2 + MD;          // [M, 4D]
  float* T1 = KV;

  // X = x_m @ W_in + b_in
  gemm_k<<<dim3(D_/64, M_/64), 256, 0, stream>>>(x_m, W_in, b_in, nullptr, X, M_, D_, DIN_, 0);
  // KV = LN(X)
  ln_k<<<M_, 256, 0, stream>>>(X, ln_kv_g, ln_kv_b, KV);
  // K/V projections
  gemm_k<<<dim3(D_/64, M_/64), 256, 0, stream>>>(KV, Wk, bk, nullptr, Kp, M_, D_, D_, 0);
  gemm_k<<<dim3(D_/64, M_/64), 256, 0, stream>>>(KV, Wv, bv, nullptr, Vp, M_, D_, D_, 0);

  for (int kk = 0; kk < K_; ++kk) {
    // Xk = X*gate; T1 = LN(Xk)
    scale_ln_k<<<M_, 256, 0, stream>>>(X, A, kk, ln_q_g, ln_q_b, Xk, T1);
    // q = T1 @ Wq + bq
    gemm_k<<<dim3(D_/64, M_/64), 256, 0, stream>>>(T1, Wq, bq, nullptr, T2, M_, D_, D_, 0);
    // T1 = banded attention(q=T2, Kp, Vp)
    attn_k<<<B_*H_*T_, 64, 0, stream>>>(T2, Kp, Vp, T1);
    // y (in Xk) = T1 @ Wo + bo + Xk
    gemm_k<<<dim3(D_/64, M_/64), 256, 0, stream>>>(T1, Wo, bo, Xk, Xk, M_, D_, D_, 0);
    // T1 = LN(y)
    ln_k<<<M_, 256, 0, stream>>>(Xk, ln_f_g, ln_f_b, T1);
    // H1 = gelu(T1 @ W1 + b1)
    gemm_k<<<dim3((4*D_)/64, M_/64), 256, 0, stream>>>(T1, W1, b1, nullptr, H1, M_, 4*D_, D_, 1);
    // T2 = H1 @ W2 + b2
    gemm_k<<<dim3(D_/64, M_/64), 256, 0, stream>>>(H1, W2, b2, nullptr, T2, M_, D_, 4*D_, 0);
    // out_k = LN(y + T2 + tag), scattered into concat layout
    final_ln_k<<<M_, 256, 0, stream>>>(Xk, T2, tags, kk, ln_s_g, ln_s_b, out);
  }
}

// Round 2
// 788.693 us; speedup vs baseline: 1.9389x; 1.9389x over previous
//
#include <hip/hip_runtime.h>
#include <hip/hip_bf16.h>
#include <math.h>

#define B_    4
#define T_    1536
#define DIN_  512
#define D_    512
#define K_    2
#define H_    8
#define BAND_ 24
#define DH_   64
#define M_    (B_*T_)      // 6144 rows
#define ALPHA_ 6.0f
#define BETA_  0.5f
#define EPS_   1e-5f

using bf8  = __attribute__((ext_vector_type(8))) short;   // 8 bf16 (4 VGPRs)
using f32x4 = __attribute__((ext_vector_type(4))) float;  // 4 fp32 acc

__device__ __forceinline__ void async_copy16(const void* g, void* l) {
  __builtin_amdgcn_global_load_lds(
      (const __attribute__((address_space(1))) unsigned int*)g,
      (__attribute__((address_space(3))) unsigned int*)l, 16, 0, 0);
}

__device__ __forceinline__ short f2bf(float v) {
  __hip_bfloat16 h = (__hip_bfloat16)v;
  return *(short*)&h;
}

// ---------------- bf16 MFMA GEMM: C = A[M,Kd] @ Bt[N,Kd]^T + bias (+res fp32) (+gelu)
// flags: 1 = gelu, 2 = bf16 output
__global__ __launch_bounds__(256) void gemm_bt_k(
    const short* __restrict__ A, const short* __restrict__ Bt,
    const float* __restrict__ bias, const float* __restrict__ res,
    void* __restrict__ Cout, int M, int N, int Kd, int flags) {
  __shared__ short lA[128 * 64];
  __shared__ short lB[128 * 64];
  const int tid  = threadIdx.x;
  const int wave = tid >> 6, lane = tid & 63;
  const int block_m = blockIdx.y * 128, block_n = blockIdx.x * 128;
  const int wm = (wave & 1) * 64, wn = (wave >> 1) * 64;
  f32x4 acc[4][4] = {};

  for (int k0 = 0; k0 < Kd; k0 += 64) {
    __syncthreads();               // previous tile's LDS reads complete
#pragma unroll
    for (int i = 0; i < 4; ++i) {
      const int c   = wave * 256 + i * 64 + lane;     // chunk of 8 bf16
      const int row = c >> 3, kin = (c & 7) * 8;
      // wave-uniform LDS base; lane lands at base + lane*16B => element c*8
      async_copy16(A  + (size_t)(block_m + row) * Kd + k0 + kin,
                   &lA[(wave * 256 + i * 64) * 8]);
      async_copy16(Bt + (size_t)(block_n + row) * Kd + k0 + kin,
                   &lB[(wave * 256 + i * 64) * 8]);
    }
    __syncthreads();               // barrier drains vmcnt => LDS tiles ready
#pragma unroll
    for (int ks = 0; ks < 2; ++ks) {
      bf8 af[4], bfr[4];
#pragma unroll
      for (int i = 0; i < 4; ++i)
        af[i] = *(const bf8*)&lA[(wm + i * 16 + (lane & 15)) * 64 + ks * 32 + (lane >> 4) * 8];
#pragma unroll
      for (int j = 0; j < 4; ++j)
        bfr[j] = *(const bf8*)&lB[(wn + j * 16 + (lane & 15)) * 64 + ks * 32 + (lane >> 4) * 8];
#pragma unroll
      for (int i = 0; i < 4; ++i)
#pragma unroll
        for (int j = 0; j < 4; ++j)
          acc[i][j] = __builtin_amdgcn_mfma_f32_16x16x32_bf16(af[i], bfr[j], acc[i][j], 0, 0, 0);
    }
  }

  const int do_gelu = flags & 1, out_bf = flags & 2;
#pragma unroll
  for (int i = 0; i < 4; ++i) {
    const int mbase = block_m + wm + i * 16 + (lane >> 4) * 4;
#pragma unroll
    for (int j = 0; j < 4; ++j) {
      const int col = block_n + wn + j * 16 + (lane & 15);
      const float bb = bias[col];
#pragma unroll
      for (int r = 0; r < 4; ++r) {
        const int row = mbase + r;
        float v = acc[i][j][r] + bb;
        if (res) v += res[(size_t)row * N + col];
        if (do_gelu) v = 0.5f * v * (1.0f + erff(v * 0.70710678118654752f));
        if (out_bf) ((short*)Cout)[(size_t)row * N + col] = f2bf(v);
        else        ((float*)Cout)[(size_t)row * N + col] = v;
      }
    }
  }
}

// ---------------- transpose + convert: W[K,N] fp32 -> Wt[N,K] bf16
__global__ __launch_bounds__(256) void tconv_k(const float* __restrict__ W,
                                               short* __restrict__ Wt, int K, int N) {
  __shared__ float s[32][33];
  const int tx = threadIdx.x & 31, ty = threadIdx.x >> 5;  // ty 0..7
  const int k0 = blockIdx.y * 32, n0 = blockIdx.x * 32;
#pragma unroll
  for (int r = 0; r < 4; ++r)
    s[ty * 4 + r][tx] = W[(size_t)(k0 + ty * 4 + r) * N + n0 + tx];
  __syncthreads();
#pragma unroll
  for (int r = 0; r < 4; ++r)
    Wt[(size_t)(n0 + ty * 4 + r) * K + k0 + tx] = f2bf(s[tx][ty * 4 + r]);
}

// ---------------- fp32 -> bf16 elementwise
__global__ void cvt_k(const float* __restrict__ x, short* __restrict__ y, int n) {
  const int i = blockIdx.x * blockDim.x + threadIdx.x;
  if (i < n) y[i] = f2bf(x[i]);
}

// ---------------- block reduction helper (256 threads)
__device__ __forceinline__ float block_sum(float s, float* red, int tid) {
  red[tid] = s; __syncthreads();
  for (int o = 128; o > 0; o >>= 1) {
    if (tid < o) red[tid] += red[tid + o];
    __syncthreads();
  }
  float r = red[0];
  __syncthreads();
  return r;
}

// ---------------- LayerNorm: out(bf16) = LN(in) * g + b
__global__ __launch_bounds__(256) void ln_k(const float* __restrict__ in,
                                            const float* __restrict__ g,
                                            const float* __restrict__ b,
                                            short* __restrict__ out) {
  __shared__ float red[256];
  const int row = blockIdx.x, tid = threadIdx.x;
  const float* x = in + (size_t)row * D_;
  const float v0 = x[tid], v1 = x[tid + 256];
  const float mean = block_sum(v0 + v1, red, tid) * (1.0f / D_);
  const float d0 = v0 - mean, d1 = v1 - mean;
  const float var = block_sum(d0 * d0 + d1 * d1, red, tid) * (1.0f / D_);
  const float inv = rsqrtf(var + EPS_);
  out[(size_t)row * D_ + tid]       = f2bf(d0 * inv * g[tid]       + b[tid]);
  out[(size_t)row * D_ + tid + 256] = f2bf(d1 * inv * g[tid + 256] + b[tid + 256]);
}

// ---------------- gate + LN: Xk(fp32) = X*sigmoid; out(bf16) = LN(Xk)
__global__ __launch_bounds__(256) void scale_ln_k(
    const float* __restrict__ X, const float* __restrict__ Ain, int kk,
    const float* __restrict__ g, const float* __restrict__ b,
    float* __restrict__ Xk, short* __restrict__ out) {
  __shared__ float red[256];
  const int row = blockIdx.x, tid = threadIdx.x;
  const float a = Ain[(size_t)row * K_ + kk];
  const float w = 1.0f / (1.0f + expf(-ALPHA_ * (a - BETA_)));
  const float v0 = X[(size_t)row * D_ + tid] * w;
  const float v1 = X[(size_t)row * D_ + tid + 256] * w;
  Xk[(size_t)row * D_ + tid] = v0;
  Xk[(size_t)row * D_ + tid + 256] = v1;
  const float mean = block_sum(v0 + v1, red, tid) * (1.0f / D_);
  const float d0 = v0 - mean, d1 = v1 - mean;
  const float var = block_sum(d0 * d0 + d1 * d1, red, tid) * (1.0f / D_);
  const float inv = rsqrtf(var + EPS_);
  out[(size_t)row * D_ + tid]       = f2bf(d0 * inv * g[tid]       + b[tid]);
  out[(size_t)row * D_ + tid + 256] = f2bf(d1 * inv * g[tid + 256] + b[tid + 256]);
}

// ---------------- final: out[b, kk*T+t, :] = LN(y + h2 + tag)  (fp32 out)
__global__ __launch_bounds__(256) void final_ln_k(
    const float* __restrict__ y, const float* __restrict__ h2,
    const float* __restrict__ tags, int kk,
    const float* __restrict__ g, const float* __restrict__ b,
    float* __restrict__ out) {
  __shared__ float red[256];
  const int row = blockIdx.x, tid = threadIdx.x;
  const int bb = row / T_, t = row % T_;
  const size_t orow = (size_t)bb * (K_ * T_) + (size_t)kk * T_ + t;
  const float v0 = y[(size_t)row * D_ + tid] + h2[(size_t)row * D_ + tid]
                 + tags[(size_t)kk * D_ + tid];
  const float v1 = y[(size_t)row * D_ + tid + 256] + h2[(size_t)row * D_ + tid + 256]
                 + tags[(size_t)kk * D_ + tid + 256];
  const float mean = block_sum(v0 + v1, red, tid) * (1.0f / D_);
  const float d0 = v0 - mean, d1 = v1 - mean;
  const float var = block_sum(d0 * d0 + d1 * d1, red, tid) * (1.0f / D_);
  const float inv = rsqrtf(var + EPS_);
  out[orow * D_ + tid]       = d0 * inv * g[tid]       + b[tid];
  out[orow * D_ + tid + 256] = d1 * inv * g[tid + 256] + b[tid + 256];
}

// ---------------- banded attention: one wave per (b,h,t); q fp32, out bf16
__global__ __launch_bounds__(64) void attn_k(
    const float* __restrict__ q, const float* __restrict__ Kp,
    const float* __restrict__ Vp, short* __restrict__ out) {
  const int idx = blockIdx.x;             // (b*H + h)*T + t
  const int t = idx % T_;
  const int h = (idx / T_) % H_;
  const int b = idx / (T_ * H_);
  const int lane = threadIdx.x;
  const int row = b * T_ + t;
  __shared__ float sq[64];
  __shared__ float sp[64];
  sq[lane] = q[(size_t)row * D_ + h * DH_ + lane];
  __syncthreads();

  const int s = t - BAND_ + lane;
  const bool valid = (lane < 2 * BAND_ + 1) && (s >= 0) && (s < T_);
  float score = -1e30f;
  if (valid) {
    const float* kr = Kp + ((size_t)(b * T_ + s) * D_ + h * DH_);
    float sum = 0.0f;
#pragma unroll
    for (int d = 0; d < DH_; ++d) sum = fmaf(sq[d], kr[d], sum);
    score = sum * 0.125f;
  }
  float mx = score;
  for (int o = 32; o > 0; o >>= 1) mx = fmaxf(mx, __shfl_xor(mx, o));
  const float p = valid ? expf(score - mx) : 0.0f;
  float se = p;
  for (int o = 32; o > 0; o >>= 1) se += __shfl_xor(se, o);
  sp[lane] = p / se;
  __syncthreads();

  float acc = 0.0f;
#pragma unroll
  for (int j = 0; j < 2 * BAND_ + 1; ++j) {
    const int ss = t - BAND_ + j;
    if (ss >= 0 && ss < T_)
      acc = fmaf(sp[j], Vp[(size_t)(b * T_ + ss) * D_ + h * DH_ + lane], acc);
  }
  out[(size_t)row * D_ + h * DH_ + lane] = f2bf(acc);
}

extern "C" void kernel_launch(void* const* d_in, const int* in_sizes, int n_in,
                              void* d_out, int out_size, void* d_ws, size_t ws_size,
                              hipStream_t stream) {
  const float* x_m    = (const float*)d_in[0];
  const float* A      = (const float*)d_in[1];
  const float* W_in   = (const float*)d_in[2];
  const float* b_in   = (const float*)d_in[3];
  const float* ln_q_g = (const float*)d_in[4];
  const float* ln_q_b = (const float*)d_in[5];
  const float* ln_kv_g= (const float*)d_in[6];
  const float* ln_kv_b= (const float*)d_in[7];
  const float* Wq     = (const float*)d_in[8];
  const float* bq     = (const float*)d_in[9];
  const float* Wk     = (const float*)d_in[10];
  const float* bk     = (const float*)d_in[11];
  const float* Wv     = (const float*)d_in[12];
  const float* bv     = (const float*)d_in[13];
  const float* Wo     = (const float*)d_in[14];
  const float* bo     = (const float*)d_in[15];
  const float* ln_f_g = (const float*)d_in[16];
  const float* ln_f_b = (const float*)d_in[17];
  const float* W1     = (const float*)d_in[18];
  const float* b1     = (const float*)d_in[19];
  const float* W2     = (const float*)d_in[20];
  const float* b2     = (const float*)d_in[21];
  const float* ln_s_g = (const float*)d_in[22];
  const float* ln_s_b = (const float*)d_in[23];
  const float* tags   = (const float*)d_in[24];
  float* out = (float*)d_out;

  const size_t MD = (size_t)M_ * D_;
  float* X  = (float*)d_ws;            // [M,D] fp32
  float* Kp = X  + MD;
  float* Vp = Kp + MD;
  float* Xk = Vp + MD;
  float* T2 = Xk + MD;                 // q, then W2 out
  short* xb  = (short*)(T2 + MD);      // bf16 buffers
  short* KVb = xb  + MD;
  short* LNb = KVb + MD;
  short* H1b = LNb + MD;               // [M, 4D] bf16
  short* WtIn = H1b + (size_t)M_ * 4 * D_;
  short* WtQ  = WtIn + (size_t)D_ * DIN_;
  short* WtK  = WtQ  + (size_t)D_ * D_;
  short* WtV  = WtK  + (size_t)D_ * D_;
  short* WtO  = WtV  + (size_t)D_ * D_;
  short* Wt1  = WtO  + (size_t)D_ * D_;      // [4D, D]
  short* Wt2  = Wt1  + (size_t)4 * D_ * D_;  // [D, 4D]

  // ---- weight prep (bf16, transposed to [N,K]) + x_m cast
  cvt_k<<<(M_ * DIN_ + 255) / 256, 256, 0, stream>>>(x_m, xb, M_ * DIN_);
  tconv_k<<<dim3(D_/32,    DIN_/32),  256, 0, stream>>>(W_in, WtIn, DIN_, D_);
  tconv_k<<<dim3(D_/32,    D_/32),    256, 0, stream>>>(Wq,   WtQ,  D_,   D_);
  tconv_k<<<dim3(D_/32,    D_/32),    256, 0, stream>>>(Wk,   WtK,  D_,   D_);
  tconv_k<<<dim3(D_/32,    D_/32),    256, 0, stream>>>(Wv,   WtV,  D_,   D_);
  tconv_k<<<dim3(D_/32,    D_/32),    256, 0, stream>>>(Wo,   WtO,  D_,   D_);
  tconv_k<<<dim3((4*D_)/32, D_/32),   256, 0, stream>>>(W1,   Wt1,  D_,   4*D_);
  tconv_k<<<dim3(D_/32,  (4*D_)/32),  256, 0, stream>>>(W2,   Wt2,  4*D_, D_);

  // X = x_m @ W_in + b_in
  gemm_bt_k<<<dim3(D_/128, M_/128), 256, 0, stream>>>(xb, WtIn, b_in, nullptr, X, M_, D_, DIN_, 0);
  // KVb = LN(X)
  ln_k<<<M_, 256, 0, stream>>>(X, ln_kv_g, ln_kv_b, KVb);
  // K/V projections (fp32 out)
  gemm_bt_k<<<dim3(D_/128, M_/128), 256, 0, stream>>>(KVb, WtK, bk, nullptr, Kp, M_, D_, D_, 0);
  gemm_bt_k<<<dim3(D_/128, M_/128), 256, 0, stream>>>(KVb, WtV, bv, nullptr, Vp, M_, D_, D_, 0);

  for (int kk = 0; kk < K_; ++kk) {
    scale_ln_k<<<M_, 256, 0, stream>>>(X, A, kk, ln_q_g, ln_q_b, Xk, LNb);
    gemm_bt_k<<<dim3(D_/128, M_/128), 256, 0, stream>>>(LNb, WtQ, bq, nullptr, T2, M_, D_, D_, 0);
    attn_k<<<B_*H_*T_, 64, 0, stream>>>(T2, Kp, Vp, LNb);
    gemm_bt_k<<<dim3(D_/128, M_/128), 256, 0, stream>>>(LNb, WtO, bo, Xk, Xk, M_, D_, D_, 0);
    ln_k<<<M_, 256, 0, stream>>>(Xk, ln_f_g, ln_f_b, LNb);
    gemm_bt_k<<<dim3((4*D_)/128, M_/128), 256, 0, stream>>>(LNb, Wt1, b1, nullptr, H1b, M_, 4*D_, D_, 3);
    gemm_bt_k<<<dim3(D_/128, M_/128), 256, 0, stream>>>(H1b, Wt2, b2, nullptr, T2, M_, D_, 4*D_, 0);
    final_ln_k<<<M_, 256, 0, stream>>>(Xk, T2, tags, kk, ln_s_g, ln_s_b, out);
  }
}

// Round 3
// 616.802 us; speedup vs baseline: 2.4792x; 1.2787x over previous
//
#include <hip/hip_runtime.h>
#include <hip/hip_bf16.h>
#include <math.h>

#define B_    4
#define T_    1536
#define DIN_  512
#define D_    512
#define K_    2
#define H_    8
#define BAND_ 24
#define DH_   64
#define M_    (B_*T_)      // 6144 rows
#define ALPHA_ 6.0f
#define BETA_  0.5f
#define EPS_   1e-5f

using bf8  = __attribute__((ext_vector_type(8))) short;   // 8 bf16 (4 VGPRs)
using f32x4 = __attribute__((ext_vector_type(4))) float;  // 4 fp32 acc

__device__ __forceinline__ void async_copy16(const void* g, void* l) {
  __builtin_amdgcn_global_load_lds(
      (const __attribute__((address_space(1))) unsigned int*)g,
      (__attribute__((address_space(3))) unsigned int*)l, 16, 0, 0);
}

__device__ __forceinline__ short f2bf(float v) {
  __hip_bfloat16 h = (__hip_bfloat16)v;
  return *(short*)&h;
}
__device__ __forceinline__ float bf2f(short s) {
  union { unsigned u; float f; } c;
  c.u = ((unsigned)(unsigned short)s) << 16;
  return c.f;
}

// ---------------- bf16 MFMA GEMM: C = A[M,Kd] @ Bt[N,Kd]^T + bias (+res fp32) (+gelu)
// flags: 1 = gelu, 2 = bf16 output
__global__ __launch_bounds__(256) void gemm_bt_k(
    const short* __restrict__ A, const short* __restrict__ Bt,
    const float* __restrict__ bias, const float* __restrict__ res,
    void* __restrict__ Cout, int M, int N, int Kd, int flags) {
  __shared__ short lA[128 * 64];
  __shared__ short lB[128 * 64];
  const int tid  = threadIdx.x;
  const int wave = tid >> 6, lane = tid & 63;
  const int block_m = blockIdx.y * 128, block_n = blockIdx.x * 128;
  const int wm = (wave & 1) * 64, wn = (wave >> 1) * 64;
  f32x4 acc[4][4] = {};

  for (int k0 = 0; k0 < Kd; k0 += 64) {
    __syncthreads();               // previous tile's LDS reads complete
#pragma unroll
    for (int i = 0; i < 4; ++i) {
      const int c   = wave * 256 + i * 64 + lane;     // chunk of 8 bf16
      const int row = c >> 3, kin = (c & 7) * 8;
      async_copy16(A  + (size_t)(block_m + row) * Kd + k0 + kin,
                   &lA[(wave * 256 + i * 64) * 8]);
      async_copy16(Bt + (size_t)(block_n + row) * Kd + k0 + kin,
                   &lB[(wave * 256 + i * 64) * 8]);
    }
    __syncthreads();               // barrier drains vmcnt => LDS tiles ready
#pragma unroll
    for (int ks = 0; ks < 2; ++ks) {
      bf8 af[4], bfr[4];
#pragma unroll
      for (int i = 0; i < 4; ++i)
        af[i] = *(const bf8*)&lA[(wm + i * 16 + (lane & 15)) * 64 + ks * 32 + (lane >> 4) * 8];
#pragma unroll
      for (int j = 0; j < 4; ++j)
        bfr[j] = *(const bf8*)&lB[(wn + j * 16 + (lane & 15)) * 64 + ks * 32 + (lane >> 4) * 8];
#pragma unroll
      for (int i = 0; i < 4; ++i)
#pragma unroll
        for (int j = 0; j < 4; ++j)
          acc[i][j] = __builtin_amdgcn_mfma_f32_16x16x32_bf16(af[i], bfr[j], acc[i][j], 0, 0, 0);
    }
  }

  const int do_gelu = flags & 1, out_bf = flags & 2;
#pragma unroll
  for (int i = 0; i < 4; ++i) {
    const int mbase = block_m + wm + i * 16 + (lane >> 4) * 4;
#pragma unroll
    for (int j = 0; j < 4; ++j) {
      const int col = block_n + wn + j * 16 + (lane & 15);
      const float bb = bias[col];
#pragma unroll
      for (int r = 0; r < 4; ++r) {
        const int row = mbase + r;
        float v = acc[i][j][r] + bb;
        if (res) v += res[(size_t)row * N + col];
        if (do_gelu) v = 0.5f * v * (1.0f + erff(v * 0.70710678118654752f));
        if (out_bf) ((short*)Cout)[(size_t)row * N + col] = f2bf(v);
        else        ((float*)Cout)[(size_t)row * N + col] = v;
      }
    }
  }
}

// ---------------- transpose + convert: W[K,N] fp32 -> Wt[N,K] bf16
__global__ __launch_bounds__(256) void tconv_k(const float* __restrict__ W,
                                               short* __restrict__ Wt, int K, int N) {
  __shared__ float s[32][33];
  const int tx = threadIdx.x & 31, ty = threadIdx.x >> 5;  // ty 0..7
  const int k0 = blockIdx.y * 32, n0 = blockIdx.x * 32;
#pragma unroll
  for (int r = 0; r < 4; ++r)
    s[ty * 4 + r][tx] = W[(size_t)(k0 + ty * 4 + r) * N + n0 + tx];
  __syncthreads();
#pragma unroll
  for (int r = 0; r < 4; ++r)
    Wt[(size_t)(n0 + ty * 4 + r) * K + k0 + tx] = f2bf(s[tx][ty * 4 + r]);
}

// ---------------- fp32 -> bf16 elementwise
__global__ void cvt_k(const float* __restrict__ x, short* __restrict__ y, int n) {
  const int i = blockIdx.x * blockDim.x + threadIdx.x;
  if (i < n) y[i] = f2bf(x[i]);
}

// ---------------- block reduction helper (256 threads)
__device__ __forceinline__ float block_sum(float s, float* red, int tid) {
  red[tid] = s; __syncthreads();
  for (int o = 128; o > 0; o >>= 1) {
    if (tid < o) red[tid] += red[tid + o];
    __syncthreads();
  }
  float r = red[0];
  __syncthreads();
  return r;
}

// ---------------- LayerNorm: out(bf16) = LN(in) * g + b
__global__ __launch_bounds__(256) void ln_k(const float* __restrict__ in,
                                            const float* __restrict__ g,
                                            const float* __restrict__ b,
                                            short* __restrict__ out) {
  __shared__ float red[256];
  const int row = blockIdx.x, tid = threadIdx.x;
  const float* x = in + (size_t)row * D_;
  const float v0 = x[tid], v1 = x[tid + 256];
  const float mean = block_sum(v0 + v1, red, tid) * (1.0f / D_);
  const float d0 = v0 - mean, d1 = v1 - mean;
  const float var = block_sum(d0 * d0 + d1 * d1, red, tid) * (1.0f / D_);
  const float inv = rsqrtf(var + EPS_);
  out[(size_t)row * D_ + tid]       = f2bf(d0 * inv * g[tid]       + b[tid]);
  out[(size_t)row * D_ + tid + 256] = f2bf(d1 * inv * g[tid + 256] + b[tid + 256]);
}

// ---------------- gate + LN: Xk(fp32) = X*sigmoid; out(bf16) = LN(Xk)
__global__ __launch_bounds__(256) void scale_ln_k(
    const float* __restrict__ X, const float* __restrict__ Ain, int kk,
    const float* __restrict__ g, const float* __restrict__ b,
    float* __restrict__ Xk, short* __restrict__ out) {
  __shared__ float red[256];
  const int row = blockIdx.x, tid = threadIdx.x;
  const float a = Ain[(size_t)row * K_ + kk];
  const float w = 1.0f / (1.0f + expf(-ALPHA_ * (a - BETA_)));
  const float v0 = X[(size_t)row * D_ + tid] * w;
  const float v1 = X[(size_t)row * D_ + tid + 256] * w;
  Xk[(size_t)row * D_ + tid] = v0;
  Xk[(size_t)row * D_ + tid + 256] = v1;
  const float mean = block_sum(v0 + v1, red, tid) * (1.0f / D_);
  const float d0 = v0 - mean, d1 = v1 - mean;
  const float var = block_sum(d0 * d0 + d1 * d1, red, tid) * (1.0f / D_);
  const float inv = rsqrtf(var + EPS_);
  out[(size_t)row * D_ + tid]       = f2bf(d0 * inv * g[tid]       + b[tid]);
  out[(size_t)row * D_ + tid + 256] = f2bf(d1 * inv * g[tid + 256] + b[tid + 256]);
}

// ---------------- final: out[b, kk*T+t, :] = LN(y + h2 + tag)  (fp32 out)
__global__ __launch_bounds__(256) void final_ln_k(
    const float* __restrict__ y, const float* __restrict__ h2,
    const float* __restrict__ tags, int kk,
    const float* __restrict__ g, const float* __restrict__ b,
    float* __restrict__ out) {
  __shared__ float red[256];
  const int row = blockIdx.x, tid = threadIdx.x;
  const int bb = row / T_, t = row % T_;
  const size_t orow = (size_t)bb * (K_ * T_) + (size_t)kk * T_ + t;
  const float v0 = y[(size_t)row * D_ + tid] + h2[(size_t)row * D_ + tid]
                 + tags[(size_t)kk * D_ + tid];
  const float v1 = y[(size_t)row * D_ + tid + 256] + h2[(size_t)row * D_ + tid + 256]
                 + tags[(size_t)kk * D_ + tid + 256];
  const float mean = block_sum(v0 + v1, red, tid) * (1.0f / D_);
  const float d0 = v0 - mean, d1 = v1 - mean;
  const float var = block_sum(d0 * d0 + d1 * d1, red, tid) * (1.0f / D_);
  const float inv = rsqrtf(var + EPS_);
  out[orow * D_ + tid]       = d0 * inv * g[tid]       + b[tid];
  out[orow * D_ + tid + 256] = d1 * inv * g[tid + 256] + b[tid + 256];
}

// ---------------- tiled banded attention: block = (b, h, 64-query tile)
// q, Kp, Vp bf16 [M, D]; out bf16 [M, D]
#define QT_  64
#define KT_  (QT_ + 2 * BAND_)   // 112 rows
#define KS_  66                  // LDS row stride (bf16 elems): word-stride 33 => conflict-free
__global__ __launch_bounds__(256) void attn_k2(
    const short* __restrict__ q, const short* __restrict__ Kp,
    const short* __restrict__ Vp, short* __restrict__ out) {
  __shared__ short sK[KT_ * KS_];
  __shared__ short sV[KT_ * KS_];
  __shared__ short sQ[QT_ * KS_];
  __shared__ float sP[4][64];
  const int t0 = blockIdx.x * QT_;
  const int h  = blockIdx.y, b = blockIdx.z;
  const int tid = threadIdx.x;
  const int wave = tid >> 6, lane = tid & 63;
  const int rr = tid >> 5;          // 0..7 row-in-group
  const int c2 = tid & 31;          // short2 column

  // ---- stage K/V window rows [t0-BAND, t0+QT+BAND) and Q tile into LDS
  for (int r0 = 0; r0 < KT_; r0 += 8) {
    const int r = r0 + rr;
    const int s = t0 - BAND_ + r;
    short2 kv = {0, 0}, vv = {0, 0};
    if (r < KT_ && s >= 0 && s < T_) {
      const size_t g = (size_t)(b * T_ + s) * D_ + h * DH_ + c2 * 2;
      kv = *(const short2*)&Kp[g];
      vv = *(const short2*)&Vp[g];
    }
    if (r < KT_) {
      *(short2*)&sK[r * KS_ + c2 * 2] = kv;
      *(short2*)&sV[r * KS_ + c2 * 2] = vv;
    }
  }
  for (int r0 = 0; r0 < QT_; r0 += 8) {
    const int r = r0 + rr;
    const size_t g = (size_t)(b * T_ + t0 + r) * D_ + h * DH_ + c2 * 2;
    *(short2*)&sQ[r * KS_ + c2 * 2] = *(const short2*)&q[g];
  }
  __syncthreads();

  // ---- each wave processes 16 queries out of LDS
  for (int qi = 0; qi < 16; ++qi) {
    const int qq = wave * 16 + qi;       // 0..63 within tile
    const int t  = t0 + qq;
    // lane = key index j (0..48 valid); key tile row = qq + j
    float sum = 0.0f;
    if (lane < 2 * BAND_ + 1) {
      const short* kr = &sK[(qq + lane) * KS_];
      const short* qr = &sQ[qq * KS_];
#pragma unroll
      for (int d2 = 0; d2 < 32; ++d2) {
        const short2 k2 = *(const short2*)&kr[d2 * 2];
        const short2 q2 = *(const short2*)&qr[d2 * 2];
        sum = fmaf(bf2f(q2.x), bf2f(k2.x), sum);
        sum = fmaf(bf2f(q2.y), bf2f(k2.y), sum);
      }
    }
    const int s = t - BAND_ + lane;
    const bool valid = (lane < 2 * BAND_ + 1) && (s >= 0) && (s < T_);
    float score = valid ? sum * 0.125f : -1e30f;
    float mx = score;
    for (int o = 32; o > 0; o >>= 1) mx = fmaxf(mx, __shfl_xor(mx, o));
    const float p = valid ? __expf(score - mx) : 0.0f;
    float se = p;
    for (int o = 32; o > 0; o >>= 1) se += __shfl_xor(se, o);
    sP[wave][lane] = p / se;
    // lane = output dim d
    float acc = 0.0f;
#pragma unroll
    for (int j = 0; j < 2 * BAND_ + 1; ++j)
      acc = fmaf(sP[wave][j], bf2f(sV[(qq + j) * KS_ + lane]), acc);
    out[(size_t)(b * T_ + t) * D_ + h * DH_ + lane] = f2bf(acc);
  }
}

extern "C" void kernel_launch(void* const* d_in, const int* in_sizes, int n_in,
                              void* d_out, int out_size, void* d_ws, size_t ws_size,
                              hipStream_t stream) {
  const float* x_m    = (const float*)d_in[0];
  const float* A      = (const float*)d_in[1];
  const float* W_in   = (const float*)d_in[2];
  const float* b_in   = (const float*)d_in[3];
  const float* ln_q_g = (const float*)d_in[4];
  const float* ln_q_b = (const float*)d_in[5];
  const float* ln_kv_g= (const float*)d_in[6];
  const float* ln_kv_b= (const float*)d_in[7];
  const float* Wq     = (const float*)d_in[8];
  const float* bq     = (const float*)d_in[9];
  const float* Wk     = (const float*)d_in[10];
  const float* bk     = (const float*)d_in[11];
  const float* Wv     = (const float*)d_in[12];
  const float* bv     = (const float*)d_in[13];
  const float* Wo     = (const float*)d_in[14];
  const float* bo     = (const float*)d_in[15];
  const float* ln_f_g = (const float*)d_in[16];
  const float* ln_f_b = (const float*)d_in[17];
  const float* W1     = (const float*)d_in[18];
  const float* b1     = (const float*)d_in[19];
  const float* W2     = (const float*)d_in[20];
  const float* b2     = (const float*)d_in[21];
  const float* ln_s_g = (const float*)d_in[22];
  const float* ln_s_b = (const float*)d_in[23];
  const float* tags   = (const float*)d_in[24];
  float* out = (float*)d_out;

  const size_t MD = (size_t)M_ * D_;
  float* X  = (float*)d_ws;            // [M,D] fp32
  float* Xk = X  + MD;
  float* T2 = Xk + MD;                 // W2 out (fp32)
  short* xb  = (short*)(T2 + MD);      // bf16 buffers
  short* KVb = xb  + MD;
  short* LNb = KVb + MD;
  short* Kpb = LNb + MD;
  short* Vpb = Kpb + MD;
  short* qb  = Vpb + MD;
  short* H1b = qb  + MD;               // [M, 4D] bf16
  short* WtIn = H1b + (size_t)M_ * 4 * D_;
  short* WtQ  = WtIn + (size_t)D_ * DIN_;
  short* WtK  = WtQ  + (size_t)D_ * D_;
  short* WtV  = WtK  + (size_t)D_ * D_;
  short* WtO  = WtV  + (size_t)D_ * D_;
  short* Wt1  = WtO  + (size_t)D_ * D_;      // [4D, D]
  short* Wt2  = Wt1  + (size_t)4 * D_ * D_;  // [D, 4D]

  // ---- weight prep (bf16, transposed to [N,K]) + x_m cast
  cvt_k<<<(M_ * DIN_ + 255) / 256, 256, 0, stream>>>(x_m, xb, M_ * DIN_);
  tconv_k<<<dim3(D_/32,    DIN_/32),  256, 0, stream>>>(W_in, WtIn, DIN_, D_);
  tconv_k<<<dim3(D_/32,    D_/32),    256, 0, stream>>>(Wq,   WtQ,  D_,   D_);
  tconv_k<<<dim3(D_/32,    D_/32),    256, 0, stream>>>(Wk,   WtK,  D_,   D_);
  tconv_k<<<dim3(D_/32,    D_/32),    256, 0, stream>>>(Wv,   WtV,  D_,   D_);
  tconv_k<<<dim3(D_/32,    D_/32),    256, 0, stream>>>(Wo,   WtO,  D_,   D_);
  tconv_k<<<dim3((4*D_)/32, D_/32),   256, 0, stream>>>(W1,   Wt1,  D_,   4*D_);
  tconv_k<<<dim3(D_/32,  (4*D_)/32),  256, 0, stream>>>(W2,   Wt2,  4*D_, D_);

  // X = x_m @ W_in + b_in
  gemm_bt_k<<<dim3(D_/128, M_/128), 256, 0, stream>>>(xb, WtIn, b_in, nullptr, X, M_, D_, DIN_, 0);
  // KVb = LN(X)
  ln_k<<<M_, 256, 0, stream>>>(X, ln_kv_g, ln_kv_b, KVb);
  // K/V projections (bf16 out)
  gemm_bt_k<<<dim3(D_/128, M_/128), 256, 0, stream>>>(KVb, WtK, bk, nullptr, Kpb, M_, D_, D_, 2);
  gemm_bt_k<<<dim3(D_/128, M_/128), 256, 0, stream>>>(KVb, WtV, bv, nullptr, Vpb, M_, D_, D_, 2);

  for (int kk = 0; kk < K_; ++kk) {
    scale_ln_k<<<M_, 256, 0, stream>>>(X, A, kk, ln_q_g, ln_q_b, Xk, LNb);
    gemm_bt_k<<<dim3(D_/128, M_/128), 256, 0, stream>>>(LNb, WtQ, bq, nullptr, qb, M_, D_, D_, 2);
    attn_k2<<<dim3(T_/QT_, H_, B_), 256, 0, stream>>>(qb, Kpb, Vpb, LNb);
    gemm_bt_k<<<dim3(D_/128, M_/128), 256, 0, stream>>>(LNb, WtO, bo, Xk, Xk, M_, D_, D_, 0);
    ln_k<<<M_, 256, 0, stream>>>(Xk, ln_f_g, ln_f_b, LNb);
    gemm_bt_k<<<dim3((4*D_)/128, M_/128), 256, 0, stream>>>(LNb, Wt1, b1, nullptr, H1b, M_, 4*D_, D_, 3);
    gemm_bt_k<<<dim3(D_/128, M_/128), 256, 0, stream>>>(H1b, Wt2, b2, nullptr, T2, M_, D_, 4*D_, 0);
    final_ln_k<<<M_, 256, 0, stream>>>(Xk, T2, tags, kk, ln_s_g, ln_s_b, out);
  }
}

// Round 4
// 490.647 us; speedup vs baseline: 3.1167x; 1.2571x over previous
//
#include <hip/hip_runtime.h>
#include <hip/hip_bf16.h>
#include <math.h>

#define B_    4
#define T_    1536
#define DIN_  512
#define D_    512
#define K_    2
#define H_    8
#define BAND_ 24
#define DH_   64
#define M_    (B_*T_)      // 6144 rows
#define M2_   (2*M_)       // both streams batched
#define ALPHA_ 6.0f
#define BETA_  0.5f
#define EPS_   1e-5f

using bf8  = __attribute__((ext_vector_type(8))) short;   // 8 bf16 (4 VGPRs)
using f32x4 = __attribute__((ext_vector_type(4))) float;  // 4 fp32 acc

__device__ __forceinline__ void async_copy16(const void* g, void* l) {
  __builtin_amdgcn_global_load_lds(
      (const __attribute__((address_space(1))) unsigned int*)g,
      (__attribute__((address_space(3))) unsigned int*)l, 16, 0, 0);
}

__device__ __forceinline__ short f2bf(float v) {
  __hip_bfloat16 h = (__hip_bfloat16)v;
  return *(short*)&h;
}
__device__ __forceinline__ float bf2f(short s) {
  union { unsigned u; float f; } c;
  c.u = ((unsigned)(unsigned short)s) << 16;
  return c.f;
}

// ---------------- bf16 MFMA GEMM: C = A[M,Kd] @ Bt[N,Kd]^T + bias (+res fp32) (+gelu)
// flags: 1 = gelu, 2 = bf16 output.  Tile BM x BN, 4 waves in 2x2, wave tile NI*16 x NJ*16.
template<int BM, int BN, int NI, int NJ>
__global__ __launch_bounds__(256) void gemm_bt_t(
    const short* __restrict__ A, const short* __restrict__ Bt,
    const float* __restrict__ bias, const float* __restrict__ res,
    void* __restrict__ Cout, int M, int N, int Kd, int flags) {
  __shared__ short lA[BM * 64];
  __shared__ short lB[BN * 64];
  const int tid  = threadIdx.x;
  const int wave = tid >> 6, lane = tid & 63;
  const int block_m = blockIdx.y * BM, block_n = blockIdx.x * BN;
  const int wm = (wave & 1) * (BM / 2), wn = (wave >> 1) * (BN / 2);
  f32x4 acc[NI][NJ] = {};

  for (int k0 = 0; k0 < Kd; k0 += 64) {
    __syncthreads();               // previous tile's LDS reads complete
#pragma unroll
    for (int i = 0; i < BM / 32; ++i) {
      const int cb = wave * (BM * 2) + i * 64;
      const int c  = cb + lane;                 // chunk of 8 bf16
      async_copy16(A + (size_t)(block_m + (c >> 3)) * Kd + k0 + (c & 7) * 8,
                   &lA[cb * 8]);
    }
#pragma unroll
    for (int i = 0; i < BN / 32; ++i) {
      const int cb = wave * (BN * 2) + i * 64;
      const int c  = cb + lane;
      async_copy16(Bt + (size_t)(block_n + (c >> 3)) * Kd + k0 + (c & 7) * 8,
                   &lB[cb * 8]);
    }
    __syncthreads();               // barrier drains vmcnt => LDS tiles ready
#pragma unroll
    for (int ks = 0; ks < 2; ++ks) {
      bf8 af[NI], bfr[NJ];
#pragma unroll
      for (int i = 0; i < NI; ++i)
        af[i] = *(const bf8*)&lA[(wm + i * 16 + (lane & 15)) * 64 + ks * 32 + (lane >> 4) * 8];
#pragma unroll
      for (int j = 0; j < NJ; ++j)
        bfr[j] = *(const bf8*)&lB[(wn + j * 16 + (lane & 15)) * 64 + ks * 32 + (lane >> 4) * 8];
#pragma unroll
      for (int i = 0; i < NI; ++i)
#pragma unroll
        for (int j = 0; j < NJ; ++j)
          acc[i][j] = __builtin_amdgcn_mfma_f32_16x16x32_bf16(af[i], bfr[j], acc[i][j], 0, 0, 0);
    }
  }

  const int do_gelu = flags & 1, out_bf = flags & 2;
#pragma unroll
  for (int i = 0; i < NI; ++i) {
    const int mbase = block_m + wm + i * 16 + (lane >> 4) * 4;
#pragma unroll
    for (int j = 0; j < NJ; ++j) {
      const int col = block_n + wn + j * 16 + (lane & 15);
      const float bb = bias[col];
#pragma unroll
      for (int r = 0; r < 4; ++r) {
        const int row = mbase + r;
        float v = acc[i][j][r] + bb;
        if (res) v += res[(size_t)row * N + col];
        if (do_gelu) v = 0.5f * v * (1.0f + erff(v * 0.70710678118654752f));
        if (out_bf) ((short*)Cout)[(size_t)row * N + col] = f2bf(v);
        else        ((float*)Cout)[(size_t)row * N + col] = v;
      }
    }
  }
}

// ---------------- transpose + convert: W[K,N] fp32 -> Wt[N,K] bf16
__global__ __launch_bounds__(256) void tconv_k(const float* __restrict__ W,
                                               short* __restrict__ Wt, int K, int N) {
  __shared__ float s[32][33];
  const int tx = threadIdx.x & 31, ty = threadIdx.x >> 5;  // ty 0..7
  const int k0 = blockIdx.y * 32, n0 = blockIdx.x * 32;
#pragma unroll
  for (int r = 0; r < 4; ++r)
    s[ty * 4 + r][tx] = W[(size_t)(k0 + ty * 4 + r) * N + n0 + tx];
  __syncthreads();
#pragma unroll
  for (int r = 0; r < 4; ++r)
    Wt[(size_t)(n0 + ty * 4 + r) * K + k0 + tx] = f2bf(s[tx][ty * 4 + r]);
}

// ---------------- fp32 -> bf16 elementwise
__global__ void cvt_k(const float* __restrict__ x, short* __restrict__ y, int n) {
  const int i = blockIdx.x * blockDim.x + threadIdx.x;
  if (i < n) y[i] = f2bf(x[i]);
}

// ---------------- concat two bias vectors [n]+[n] -> [2n]
__global__ void concat2_k(const float* __restrict__ a, const float* __restrict__ b,
                          float* __restrict__ o, int n) {
  const int i = blockIdx.x * blockDim.x + threadIdx.x;
  if (i < n) o[i] = a[i];
  else if (i < 2 * n) o[i] = b[i - n];
}

// ---------------- block reduction helper (256 threads)
__device__ __forceinline__ float block_sum(float s, float* red, int tid) {
  red[tid] = s; __syncthreads();
  for (int o = 128; o > 0; o >>= 1) {
    if (tid < o) red[tid] += red[tid + o];
    __syncthreads();
  }
  float r = red[0];
  __syncthreads();
  return r;
}

// ---------------- LayerNorm: out(bf16) = LN(in) * g + b  (grid = rows)
__global__ __launch_bounds__(256) void ln_k(const float* __restrict__ in,
                                            const float* __restrict__ g,
                                            const float* __restrict__ b,
                                            short* __restrict__ out) {
  __shared__ float red[256];
  const int row = blockIdx.x, tid = threadIdx.x;
  const float* x = in + (size_t)row * D_;
  const float v0 = x[tid], v1 = x[tid + 256];
  const float mean = block_sum(v0 + v1, red, tid) * (1.0f / D_);
  const float d0 = v0 - mean, d1 = v1 - mean;
  const float var = block_sum(d0 * d0 + d1 * d1, red, tid) * (1.0f / D_);
  const float inv = rsqrtf(var + EPS_);
  out[(size_t)row * D_ + tid]       = f2bf(d0 * inv * g[tid]       + b[tid]);
  out[(size_t)row * D_ + tid + 256] = f2bf(d1 * inv * g[tid + 256] + b[tid + 256]);
}

// ---------------- gate + LN, both streams: grid = 2M rows
__global__ __launch_bounds__(256) void scale_ln_k(
    const float* __restrict__ X, const float* __restrict__ Ain,
    const float* __restrict__ g, const float* __restrict__ b,
    float* __restrict__ Xk, short* __restrict__ out) {
  __shared__ float red[256];
  const int row = blockIdx.x, tid = threadIdx.x;
  const int kk = row / M_, rm = row % M_;
  const float a = Ain[(size_t)rm * K_ + kk];
  const float w = 1.0f / (1.0f + __expf(-ALPHA_ * (a - BETA_)));
  const float v0 = X[(size_t)rm * D_ + tid] * w;
  const float v1 = X[(size_t)rm * D_ + tid + 256] * w;
  Xk[(size_t)row * D_ + tid] = v0;
  Xk[(size_t)row * D_ + tid + 256] = v1;
  const float mean = block_sum(v0 + v1, red, tid) * (1.0f / D_);
  const float d0 = v0 - mean, d1 = v1 - mean;
  const float var = block_sum(d0 * d0 + d1 * d1, red, tid) * (1.0f / D_);
  const float inv = rsqrtf(var + EPS_);
  out[(size_t)row * D_ + tid]       = f2bf(d0 * inv * g[tid]       + b[tid]);
  out[(size_t)row * D_ + tid + 256] = f2bf(d1 * inv * g[tid + 256] + b[tid + 256]);
}

// ---------------- final LN, both streams: grid = 2M rows, scatter to concat layout
__global__ __launch_bounds__(256) void final_ln_k(
    const float* __restrict__ y, const float* __restrict__ h2,
    const float* __restrict__ tags,
    const float* __restrict__ g, const float* __restrict__ b,
    float* __restrict__ out) {
  __shared__ float red[256];
  const int row = blockIdx.x, tid = threadIdx.x;
  const int kk = row / M_, rm = row % M_;
  const int bb = rm / T_, t = rm % T_;
  const size_t orow = (size_t)bb * (K_ * T_) + (size_t)kk * T_ + t;
  const float v0 = y[(size_t)row * D_ + tid] + h2[(size_t)row * D_ + tid]
                 + tags[(size_t)kk * D_ + tid];
  const float v1 = y[(size_t)row * D_ + tid + 256] + h2[(size_t)row * D_ + tid + 256]
                 + tags[(size_t)kk * D_ + tid + 256];
  const float mean = block_sum(v0 + v1, red, tid) * (1.0f / D_);
  const float d0 = v0 - mean, d1 = v1 - mean;
  const float var = block_sum(d0 * d0 + d1 * d1, red, tid) * (1.0f / D_);
  const float inv = rsqrtf(var + EPS_);
  out[orow * D_ + tid]       = d0 * inv * g[tid]       + b[tid];
  out[orow * D_ + tid + 256] = d1 * inv * g[tid + 256] + b[tid + 256];
}

// ---------------- tiled banded attention, both streams
// q [2M, D] bf16; KVp [M, 2D] bf16 (cols 0..511 = K, 512..1023 = V); out [2M, D] bf16
#define QT_  64
#define KT_  (QT_ + 2 * BAND_)   // 112 rows
#define KS_  66                  // LDS row stride (bf16): word-stride 33 => conflict-free
__global__ __launch_bounds__(256) void attn_k2(
    const short* __restrict__ q, const short* __restrict__ KVp,
    short* __restrict__ out) {
  __shared__ short sK[KT_ * KS_];
  __shared__ short sV[KT_ * KS_];
  __shared__ short sQ[QT_ * KS_];
  __shared__ float sP[4][64];
  const int t0 = blockIdx.x * QT_;
  const int h  = blockIdx.y;
  const int z  = blockIdx.z;          // kk*B + b
  const int b  = z % B_;
  const int tid = threadIdx.x;
  const int wave = tid >> 6, lane = tid & 63;
  const int rr = tid >> 5;            // 0..7 row-in-group
  const int c2 = tid & 31;            // short2 column

  for (int r0 = 0; r0 < KT_; r0 += 8) {
    const int r = r0 + rr;
    const int s = t0 - BAND_ + r;
    short2 kv = {0, 0}, vv = {0, 0};
    if (r < KT_ && s >= 0 && s < T_) {
      const size_t g = (size_t)(b * T_ + s) * (2 * D_) + h * DH_ + c2 * 2;
      kv = *(const short2*)&KVp[g];
      vv = *(const short2*)&KVp[g + D_];
    }
    if (r < KT_) {
      *(short2*)&sK[r * KS_ + c2 * 2] = kv;
      *(short2*)&sV[r * KS_ + c2 * 2] = vv;
    }
  }
  for (int r0 = 0; r0 < QT_; r0 += 8) {
    const int r = r0 + rr;
    const size_t g = (size_t)(z * T_ + t0 + r) * D_ + h * DH_ + c2 * 2;
    *(short2*)&sQ[r * KS_ + c2 * 2] = *(const short2*)&q[g];
  }
  __syncthreads();

  for (int qi = 0; qi < 16; ++qi) {
    const int qq = wave * 16 + qi;       // 0..63 within tile
    const int t  = t0 + qq;
    float sum = 0.0f;
    if (lane < 2 * BAND_ + 1) {
      const short* kr = &sK[(qq + lane) * KS_];
      const short* qr = &sQ[qq * KS_];
#pragma unroll
      for (int d2 = 0; d2 < 32; ++d2) {
        const short2 k2 = *(const short2*)&kr[d2 * 2];
        const short2 q2 = *(const short2*)&qr[d2 * 2];
        sum = fmaf(bf2f(q2.x), bf2f(k2.x), sum);
        sum = fmaf(bf2f(q2.y), bf2f(k2.y), sum);
      }
    }
    const int s = t - BAND_ + lane;
    const bool valid = (lane < 2 * BAND_ + 1) && (s >= 0) && (s < T_);
    float score = valid ? sum * 0.125f : -1e30f;
    float mx = score;
    for (int o = 32; o > 0; o >>= 1) mx = fmaxf(mx, __shfl_xor(mx, o));
    const float p = valid ? __expf(score - mx) : 0.0f;
    float se = p;
    for (int o = 32; o > 0; o >>= 1) se += __shfl_xor(se, o);
    sP[wave][lane] = p / se;
    float acc = 0.0f;
#pragma unroll
    for (int j = 0; j < 2 * BAND_ + 1; ++j)
      acc = fmaf(sP[wave][j], bf2f(sV[(qq + j) * KS_ + lane]), acc);
    out[(size_t)(z * T_ + t) * D_ + h * DH_ + lane] = f2bf(acc);
  }
}

extern "C" void kernel_launch(void* const* d_in, const int* in_sizes, int n_in,
                              void* d_out, int out_size, void* d_ws, size_t ws_size,
                              hipStream_t stream) {
  const float* x_m    = (const float*)d_in[0];
  const float* A      = (const float*)d_in[1];
  const float* W_in   = (const float*)d_in[2];
  const float* b_in   = (const float*)d_in[3];
  const float* ln_q_g = (const float*)d_in[4];
  const float* ln_q_b = (const float*)d_in[5];
  const float* ln_kv_g= (const float*)d_in[6];
  const float* ln_kv_b= (const float*)d_in[7];
  const float* Wq     = (const float*)d_in[8];
  const float* bq     = (const float*)d_in[9];
  const float* Wk     = (const float*)d_in[10];
  const float* bk     = (const float*)d_in[11];
  const float* Wv     = (const float*)d_in[12];
  const float* bv     = (const float*)d_in[13];
  const float* Wo     = (const float*)d_in[14];
  const float* bo     = (const float*)d_in[15];
  const float* ln_f_g = (const float*)d_in[16];
  const float* ln_f_b = (const float*)d_in[17];
  const float* W1     = (const float*)d_in[18];
  const float* b1     = (const float*)d_in[19];
  const float* W2     = (const float*)d_in[20];
  const float* b2     = (const float*)d_in[21];
  const float* ln_s_g = (const float*)d_in[22];
  const float* ln_s_b = (const float*)d_in[23];
  const float* tags   = (const float*)d_in[24];
  float* out = (float*)d_out;

  const size_t MD = (size_t)M_ * D_;
  // fp32 buffers
  float* X   = (float*)d_ws;           // [M,D]
  float* Xk2 = X   + MD;               // [2M,D]  gated X, then y (in place)
  float* T2  = Xk2 + 2 * MD;           // [2M,D]  W2 out
  float* bkv = T2  + 2 * MD;           // [1024]
  // bf16 buffers
  short* LNb2 = (short*)(bkv + 1024);  // [2M,D]; first MD also = KV LN
  short* qb2  = LNb2 + 2 * MD;         // [2M,D]; first MD also = xb (x_m bf16)
  short* KVpb = qb2  + 2 * MD;         // [M,2D] interleaved K|V
  short* H1b  = KVpb + 2 * MD;         // [2M,4D]
  short* WtIn = H1b + (size_t)M2_ * 4 * D_;
  short* WtQ  = WtIn + (size_t)D_ * DIN_;
  short* WtKV = WtQ  + (size_t)D_ * D_;        // [2D, D]
  short* WtO  = WtKV + (size_t)2 * D_ * D_;
  short* Wt1  = WtO  + (size_t)D_ * D_;        // [4D, D]
  short* Wt2  = Wt1  + (size_t)4 * D_ * D_;    // [D, 4D]
  short* xb   = qb2;                   // alias (used before Q GEMM)
  short* KVb  = LNb2;                  // alias (used before scale_ln)

  // ---- prep: weights to bf16 [N,K], x_m to bf16, concat K/V bias
  cvt_k<<<(M_ * DIN_ + 255) / 256, 256, 0, stream>>>(x_m, xb, M_ * DIN_);
  concat2_k<<<4, 256, 0, stream>>>(bk, bv, bkv, D_);
  tconv_k<<<dim3(D_/32,    DIN_/32),  256, 0, stream>>>(W_in, WtIn, DIN_, D_);
  tconv_k<<<dim3(D_/32,    D_/32),    256, 0, stream>>>(Wq,   WtQ,  D_,   D_);
  tconv_k<<<dim3(D_/32,    D_/32),    256, 0, stream>>>(Wk,   WtKV, D_,   D_);
  tconv_k<<<dim3(D_/32,    D_/32),    256, 0, stream>>>(Wv,   WtKV + (size_t)D_*D_, D_, D_);
  tconv_k<<<dim3(D_/32,    D_/32),    256, 0, stream>>>(Wo,   WtO,  D_,   D_);
  tconv_k<<<dim3((4*D_)/32, D_/32),   256, 0, stream>>>(W1,   Wt1,  D_,   4*D_);
  tconv_k<<<dim3(D_/32,  (4*D_)/32),  256, 0, stream>>>(W2,   Wt2,  4*D_, D_);

  // X = x_m @ W_in + b_in           (384 blocks)
  gemm_bt_t<128,64,4,2><<<dim3(D_/64, M_/128), 256, 0, stream>>>(
      xb, WtIn, b_in, nullptr, X, M_, D_, DIN_, 0);
  // KVb = LN(X)
  ln_k<<<M_, 256, 0, stream>>>(X, ln_kv_g, ln_kv_b, KVb);
  // K|V projection, N=1024       (384 blocks)
  gemm_bt_t<128,128,4,4><<<dim3((2*D_)/128, M_/128), 256, 0, stream>>>(
      KVb, WtKV, bkv, nullptr, KVpb, M_, 2*D_, D_, 2);

  // ---- both streams batched over 2M rows
  scale_ln_k<<<M2_, 256, 0, stream>>>(X, A, ln_q_g, ln_q_b, Xk2, LNb2);
  gemm_bt_t<128,128,4,4><<<dim3(D_/128, M2_/128), 256, 0, stream>>>(
      LNb2, WtQ, bq, nullptr, qb2, M2_, D_, D_, 2);          // 384 blocks
  attn_k2<<<dim3(T_/QT_, H_, B_*K_), 256, 0, stream>>>(qb2, KVpb, LNb2);
  gemm_bt_t<128,128,4,4><<<dim3(D_/128, M2_/128), 256, 0, stream>>>(
      LNb2, WtO, bo, Xk2, Xk2, M2_, D_, D_, 0);              // y, in place
  ln_k<<<M2_, 256, 0, stream>>>(Xk2, ln_f_g, ln_f_b, LNb2);
  gemm_bt_t<128,128,4,4><<<dim3((4*D_)/128, M2_/128), 256, 0, stream>>>(
      LNb2, Wt1, b1, nullptr, H1b, M2_, 4*D_, D_, 3);        // 1536 blocks
  gemm_bt_t<128,64,4,2><<<dim3(D_/64, M2_/128), 256, 0, stream>>>(
      H1b, Wt2, b2, nullptr, T2, M2_, D_, 4*D_, 0);          // 768 blocks
  final_ln_k<<<M2_, 256, 0, stream>>>(Xk2, T2, tags, ln_s_g, ln_s_b, out);
}

// Round 5
// 435.224 us; speedup vs baseline: 3.5136x; 1.1273x over previous
//
#include <hip/hip_runtime.h>
#include <hip/hip_bf16.h>
#include <math.h>

#define B_    4
#define T_    1536
#define DIN_  512
#define D_    512
#define K_    2
#define H_    8
#define BAND_ 24
#define DH_   64
#define M_    (B_*T_)      // 6144 rows
#define M2_   (2*M_)       // both streams batched
#define ALPHA_ 6.0f
#define BETA_  0.5f
#define EPS_   1e-5f

using bf8  = __attribute__((ext_vector_type(8))) short;   // 8 bf16 (4 VGPRs)
using f32x4 = __attribute__((ext_vector_type(4))) float;  // 4 fp32 acc

__device__ __forceinline__ void async_copy16(const void* g, void* l) {
  __builtin_amdgcn_global_load_lds(
      (const __attribute__((address_space(1))) unsigned int*)g,
      (__attribute__((address_space(3))) unsigned int*)l, 16, 0, 0);
}

__device__ __forceinline__ short f2bf(float v) {
  __hip_bfloat16 h = (__hip_bfloat16)v;
  return *(short*)&h;
}
__device__ __forceinline__ float bf2f(short s) {
  union { unsigned u; float f; } c;
  c.u = ((unsigned)(unsigned short)s) << 16;
  return c.f;
}

// ---------------- bf16 MFMA GEMM: C = A[M,Kd] @ Bt[N,Kd]^T + bias (+res fp32) (+gelu)
// flags: 1 = gelu, 2 = bf16 output.  Tile BM x BN, 4 waves in 2x2, wave tile NI*16 x NJ*16.
template<int BM, int BN, int NI, int NJ>
__global__ __launch_bounds__(256) void gemm_bt_t(
    const short* __restrict__ A, const short* __restrict__ Bt,
    const float* __restrict__ bias, const float* __restrict__ res,
    void* __restrict__ Cout, int M, int N, int Kd, int flags) {
  __shared__ short lA[BM * 64];
  __shared__ short lB[BN * 64];
  const int tid  = threadIdx.x;
  const int wave = tid >> 6, lane = tid & 63;
  const int block_m = blockIdx.y * BM, block_n = blockIdx.x * BN;
  const int wm = (wave & 1) * (BM / 2), wn = (wave >> 1) * (BN / 2);
  f32x4 acc[NI][NJ] = {};

  for (int k0 = 0; k0 < Kd; k0 += 64) {
    __syncthreads();               // previous tile's LDS reads complete
#pragma unroll
    for (int i = 0; i < BM / 32; ++i) {
      const int cb = wave * (BM * 2) + i * 64;
      const int c  = cb + lane;                 // chunk of 8 bf16
      async_copy16(A + (size_t)(block_m + (c >> 3)) * Kd + k0 + (c & 7) * 8,
                   &lA[cb * 8]);
    }
#pragma unroll
    for (int i = 0; i < BN / 32; ++i) {
      const int cb = wave * (BN * 2) + i * 64;
      const int c  = cb + lane;
      async_copy16(Bt + (size_t)(block_n + (c >> 3)) * Kd + k0 + (c & 7) * 8,
                   &lB[cb * 8]);
    }
    __syncthreads();               // barrier drains vmcnt => LDS tiles ready
#pragma unroll
    for (int ks = 0; ks < 2; ++ks) {
      bf8 af[NI], bfr[NJ];
#pragma unroll
      for (int i = 0; i < NI; ++i)
        af[i] = *(const bf8*)&lA[(wm + i * 16 + (lane & 15)) * 64 + ks * 32 + (lane >> 4) * 8];
#pragma unroll
      for (int j = 0; j < NJ; ++j)
        bfr[j] = *(const bf8*)&lB[(wn + j * 16 + (lane & 15)) * 64 + ks * 32 + (lane >> 4) * 8];
#pragma unroll
      for (int i = 0; i < NI; ++i)
#pragma unroll
        for (int j = 0; j < NJ; ++j)
          acc[i][j] = __builtin_amdgcn_mfma_f32_16x16x32_bf16(af[i], bfr[j], acc[i][j], 0, 0, 0);
    }
  }

  const int do_gelu = flags & 1, out_bf = flags & 2;
#pragma unroll
  for (int i = 0; i < NI; ++i) {
    const int mbase = block_m + wm + i * 16 + (lane >> 4) * 4;
#pragma unroll
    for (int j = 0; j < NJ; ++j) {
      const int col = block_n + wn + j * 16 + (lane & 15);
      const float bb = bias[col];
#pragma unroll
      for (int r = 0; r < 4; ++r) {
        const int row = mbase + r;
        float v = acc[i][j][r] + bb;
        if (res) v += res[(size_t)row * N + col];
        if (do_gelu) v = 0.5f * v * (1.0f + erff(v * 0.70710678118654752f));
        if (out_bf) ((short*)Cout)[(size_t)row * N + col] = f2bf(v);
        else        ((float*)Cout)[(size_t)row * N + col] = v;
      }
    }
  }
}

// ---------------- transpose + convert: W[K,N] fp32 -> Wt[N,K] bf16
__global__ __launch_bounds__(256) void tconv_k(const float* __restrict__ W,
                                               short* __restrict__ Wt, int K, int N) {
  __shared__ float s[32][33];
  const int tx = threadIdx.x & 31, ty = threadIdx.x >> 5;  // ty 0..7
  const int k0 = blockIdx.y * 32, n0 = blockIdx.x * 32;
#pragma unroll
  for (int r = 0; r < 4; ++r)
    s[ty * 4 + r][tx] = W[(size_t)(k0 + ty * 4 + r) * N + n0 + tx];
  __syncthreads();
#pragma unroll
  for (int r = 0; r < 4; ++r)
    Wt[(size_t)(n0 + ty * 4 + r) * K + k0 + tx] = f2bf(s[tx][ty * 4 + r]);
}

// ---------------- fp32 -> bf16 elementwise
__global__ void cvt_k(const float* __restrict__ x, short* __restrict__ y, int n) {
  const int i = blockIdx.x * blockDim.x + threadIdx.x;
  if (i < n) y[i] = f2bf(x[i]);
}

// ---------------- concat two bias vectors [n]+[n] -> [2n]
__global__ void concat2_k(const float* __restrict__ a, const float* __restrict__ b,
                          float* __restrict__ o, int n) {
  const int i = blockIdx.x * blockDim.x + threadIdx.x;
  if (i < n) o[i] = a[i];
  else if (i < 2 * n) o[i] = b[i - n];
}

// ---------------- block reduction helper (256 threads)
__device__ __forceinline__ float block_sum(float s, float* red, int tid) {
  red[tid] = s; __syncthreads();
  for (int o = 128; o > 0; o >>= 1) {
    if (tid < o) red[tid] += red[tid + o];
    __syncthreads();
  }
  float r = red[0];
  __syncthreads();
  return r;
}

// ---------------- LayerNorm: out(bf16) = LN(in) * g + b  (grid = rows)
__global__ __launch_bounds__(256) void ln_k(const float* __restrict__ in,
                                            const float* __restrict__ g,
                                            const float* __restrict__ b,
                                            short* __restrict__ out) {
  __shared__ float red[256];
  const int row = blockIdx.x, tid = threadIdx.x;
  const float* x = in + (size_t)row * D_;
  const float v0 = x[tid], v1 = x[tid + 256];
  const float mean = block_sum(v0 + v1, red, tid) * (1.0f / D_);
  const float d0 = v0 - mean, d1 = v1 - mean;
  const float var = block_sum(d0 * d0 + d1 * d1, red, tid) * (1.0f / D_);
  const float inv = rsqrtf(var + EPS_);
  out[(size_t)row * D_ + tid]       = f2bf(d0 * inv * g[tid]       + b[tid]);
  out[(size_t)row * D_ + tid + 256] = f2bf(d1 * inv * g[tid + 256] + b[tid + 256]);
}

// ---------------- gate + LN, both streams: grid = 2M rows
__global__ __launch_bounds__(256) void scale_ln_k(
    const float* __restrict__ X, const float* __restrict__ Ain,
    const float* __restrict__ g, const float* __restrict__ b,
    float* __restrict__ Xk, short* __restrict__ out) {
  __shared__ float red[256];
  const int row = blockIdx.x, tid = threadIdx.x;
  const int kk = row / M_, rm = row % M_;
  const float a = Ain[(size_t)rm * K_ + kk];
  const float w = 1.0f / (1.0f + __expf(-ALPHA_ * (a - BETA_)));
  const float v0 = X[(size_t)rm * D_ + tid] * w;
  const float v1 = X[(size_t)rm * D_ + tid + 256] * w;
  Xk[(size_t)row * D_ + tid] = v0;
  Xk[(size_t)row * D_ + tid + 256] = v1;
  const float mean = block_sum(v0 + v1, red, tid) * (1.0f / D_);
  const float d0 = v0 - mean, d1 = v1 - mean;
  const float var = block_sum(d0 * d0 + d1 * d1, red, tid) * (1.0f / D_);
  const float inv = rsqrtf(var + EPS_);
  out[(size_t)row * D_ + tid]       = f2bf(d0 * inv * g[tid]       + b[tid]);
  out[(size_t)row * D_ + tid + 256] = f2bf(d1 * inv * g[tid + 256] + b[tid + 256]);
}

// ---------------- final LN, both streams: grid = 2M rows, scatter to concat layout
__global__ __launch_bounds__(256) void final_ln_k(
    const float* __restrict__ y, const float* __restrict__ h2,
    const float* __restrict__ tags,
    const float* __restrict__ g, const float* __restrict__ b,
    float* __restrict__ out) {
  __shared__ float red[256];
  const int row = blockIdx.x, tid = threadIdx.x;
  const int kk = row / M_, rm = row % M_;
  const int bb = rm / T_, t = rm % T_;
  const size_t orow = (size_t)bb * (K_ * T_) + (size_t)kk * T_ + t;
  const float v0 = y[(size_t)row * D_ + tid] + h2[(size_t)row * D_ + tid]
                 + tags[(size_t)kk * D_ + tid];
  const float v1 = y[(size_t)row * D_ + tid + 256] + h2[(size_t)row * D_ + tid + 256]
                 + tags[(size_t)kk * D_ + tid + 256];
  const float mean = block_sum(v0 + v1, red, tid) * (1.0f / D_);
  const float d0 = v0 - mean, d1 = v1 - mean;
  const float var = block_sum(d0 * d0 + d1 * d1, red, tid) * (1.0f / D_);
  const float inv = rsqrtf(var + EPS_);
  out[orow * D_ + tid]       = d0 * inv * g[tid]       + b[tid];
  out[orow * D_ + tid + 256] = d1 * inv * g[tid + 256] + b[tid + 256];
}

// ---------------- MFMA banded attention, both streams
// q [2M,D] bf16; KVp [M,2D] bf16 (K | V); out [2M,D] bf16
// block = (b,h,64-query tile); wave w handles queries [16w,16w+16) whose
// bands fall in key-window rows [16w, 16w+64) of the staged 112-row window.
#define QT_  64
#define KT_  (QT_ + 2 * BAND_)   // 112 rows
#define SKQ_ 72                  // row stride (shorts) for sK/sQ/sP: 144B, 16B-aligned
#define STV_ 136                 // row stride (shorts) for sVt: 272B, 16B-aligned
__global__ __launch_bounds__(256) void attn_mfma_k(
    const short* __restrict__ q, const short* __restrict__ KVp,
    short* __restrict__ out) {
  __shared__ short sK[KT_ * SKQ_];
  __shared__ short sQ[QT_ * SKQ_];
  __shared__ short sVt[DH_ * STV_];     // transposed: [dim][key row]
  __shared__ short sP[4][16 * SKQ_];
  const int t0 = blockIdx.x * QT_;
  const int h  = blockIdx.y;
  const int z  = blockIdx.z;            // kk*B + b
  const int b  = z % B_;
  const int tid = threadIdx.x;
  const int wave = tid >> 6, lane = tid & 63;
  const int rr = tid >> 5, c2 = tid & 31;

  // ---- stage K rows + V transposed + Q rows
  for (int r0 = 0; r0 < KT_; r0 += 8) {
    const int r = r0 + rr;
    const int s = t0 - BAND_ + r;
    short2 kv = {0, 0}, vv = {0, 0};
    if (s >= 0 && s < T_) {
      const size_t g = (size_t)(b * T_ + s) * (2 * D_) + h * DH_ + c2 * 2;
      kv = *(const short2*)&KVp[g];
      vv = *(const short2*)&KVp[g + D_];
    }
    *(short2*)&sK[r * SKQ_ + c2 * 2] = kv;
    sVt[(c2 * 2)     * STV_ + r] = vv.x;
    sVt[(c2 * 2 + 1) * STV_ + r] = vv.y;
  }
  for (int r0 = 0; r0 < QT_; r0 += 8) {
    const int r = r0 + rr;
    const size_t g = (size_t)(z * T_ + t0 + r) * D_ + h * DH_ + c2 * 2;
    *(short2*)&sQ[r * SKQ_ + c2 * 2] = *(const short2*)&q[g];
  }
  __syncthreads();

  const int qg  = wave * 16;            // query group base (also key window base)
  const int l15 = lane & 15, quad = lane >> 4;

  // ---- S = Q16x64 @ K64x64^T  (8 MFMAs)
  bf8 qa0 = *(const bf8*)&sQ[(qg + l15) * SKQ_ + quad * 8];
  bf8 qa1 = *(const bf8*)&sQ[(qg + l15) * SKQ_ + 32 + quad * 8];
  f32x4 acc[4];
#pragma unroll
  for (int j = 0; j < 4; ++j) {
    const bf8 kb0 = *(const bf8*)&sK[(qg + j * 16 + l15) * SKQ_ + quad * 8];
    const bf8 kb1 = *(const bf8*)&sK[(qg + j * 16 + l15) * SKQ_ + 32 + quad * 8];
    f32x4 z4 = {0.f, 0.f, 0.f, 0.f};
    acc[j] = __builtin_amdgcn_mfma_f32_16x16x32_bf16(qa0, kb0, z4, 0, 0, 0);
    acc[j] = __builtin_amdgcn_mfma_f32_16x16x32_bf16(qa1, kb1, acc[j], 0, 0, 0);
  }

  // ---- banded softmax on C-layout rows (row = quad*4+reg, col = j*16+l15)
#pragma unroll
  for (int reg = 0; reg < 4; ++reg) {
    const int i = quad * 4 + reg;       // query within group
    float sc[4];
    float mx = -1e30f;
#pragma unroll
    for (int j = 0; j < 4; ++j) {
      const int c = j * 16 + l15;       // key within 64-window
      const int s = t0 + qg - BAND_ + c;
      const int rel = c - i;            // in [0,48] when inside band
      const bool valid = (rel >= 0) && (rel <= 2 * BAND_) && (s >= 0) && (s < T_);
      sc[j] = valid ? acc[j][reg] * 0.125f : -1e30f;
      mx = fmaxf(mx, sc[j]);
    }
    for (int o = 1; o < 16; o <<= 1) mx = fmaxf(mx, __shfl_xor(mx, o));
    float p[4], se = 0.0f;
#pragma unroll
    for (int j = 0; j < 4; ++j) {
      p[j] = (sc[j] > -1e29f) ? __expf(sc[j] - mx) : 0.0f;
      se += p[j];
    }
    for (int o = 1; o < 16; o <<= 1) se += __shfl_xor(se, o);
    const float inv = 1.0f / se;
#pragma unroll
    for (int j = 0; j < 4; ++j)
      sP[wave][i * SKQ_ + j * 16 + l15] = f2bf(p[j] * inv);
  }

  // ---- O = P16x64 @ V64x64  (8 MFMAs; V from transposed LDS)
  const bf8 pa0 = *(const bf8*)&sP[wave][l15 * SKQ_ + quad * 8];
  const bf8 pa1 = *(const bf8*)&sP[wave][l15 * SKQ_ + 32 + quad * 8];
  f32x4 oacc[4] = {};
#pragma unroll
  for (int dt = 0; dt < 4; ++dt) {
    const bf8 vb0 = *(const bf8*)&sVt[(dt * 16 + l15) * STV_ + qg + quad * 8];
    const bf8 vb1 = *(const bf8*)&sVt[(dt * 16 + l15) * STV_ + qg + 32 + quad * 8];
    oacc[dt] = __builtin_amdgcn_mfma_f32_16x16x32_bf16(pa0, vb0, oacc[dt], 0, 0, 0);
    oacc[dt] = __builtin_amdgcn_mfma_f32_16x16x32_bf16(pa1, vb1, oacc[dt], 0, 0, 0);
  }
#pragma unroll
  for (int dt = 0; dt < 4; ++dt)
#pragma unroll
    for (int reg = 0; reg < 4; ++reg) {
      const int i = quad * 4 + reg;
      out[(size_t)(z * T_ + t0 + qg + i) * D_ + h * DH_ + dt * 16 + l15] =
          f2bf(oacc[dt][reg]);
    }
}

extern "C" void kernel_launch(void* const* d_in, const int* in_sizes, int n_in,
                              void* d_out, int out_size, void* d_ws, size_t ws_size,
                              hipStream_t stream) {
  const float* x_m    = (const float*)d_in[0];
  const float* A      = (const float*)d_in[1];
  const float* W_in   = (const float*)d_in[2];
  const float* b_in   = (const float*)d_in[3];
  const float* ln_q_g = (const float*)d_in[4];
  const float* ln_q_b = (const float*)d_in[5];
  const float* ln_kv_g= (const float*)d_in[6];
  const float* ln_kv_b= (const float*)d_in[7];
  const float* Wq     = (const float*)d_in[8];
  const float* bq     = (const float*)d_in[9];
  const float* Wk     = (const float*)d_in[10];
  const float* bk     = (const float*)d_in[11];
  const float* Wv     = (const float*)d_in[12];
  const float* bv     = (const float*)d_in[13];
  const float* Wo     = (const float*)d_in[14];
  const float* bo     = (const float*)d_in[15];
  const float* ln_f_g = (const float*)d_in[16];
  const float* ln_f_b = (const float*)d_in[17];
  const float* W1     = (const float*)d_in[18];
  const float* b1     = (const float*)d_in[19];
  const float* W2     = (const float*)d_in[20];
  const float* b2     = (const float*)d_in[21];
  const float* ln_s_g = (const float*)d_in[22];
  const float* ln_s_b = (const float*)d_in[23];
  const float* tags   = (const float*)d_in[24];
  float* out = (float*)d_out;

  const size_t MD = (size_t)M_ * D_;
  // fp32 buffers
  float* X   = (float*)d_ws;           // [M,D]
  float* Xk2 = X   + MD;               // [2M,D]  gated X, then y (in place)
  float* T2  = Xk2 + 2 * MD;           // [2M,D]  W2 out
  float* bkv = T2  + 2 * MD;           // [1024]
  // bf16 buffers
  short* LNb2 = (short*)(bkv + 1024);  // [2M,D]; first MD also = KV LN
  short* qb2  = LNb2 + 2 * MD;         // [2M,D]; first MD also = xb (x_m bf16)
  short* KVpb = qb2  + 2 * MD;         // [M,2D] interleaved K|V
  short* H1b  = KVpb + 2 * MD;         // [2M,4D]
  short* WtIn = H1b + (size_t)M2_ * 4 * D_;
  short* WtQ  = WtIn + (size_t)D_ * DIN_;
  short* WtKV = WtQ  + (size_t)D_ * D_;        // [2D, D]
  short* WtO  = WtKV + (size_t)2 * D_ * D_;
  short* Wt1  = WtO  + (size_t)D_ * D_;        // [4D, D]
  short* Wt2  = Wt1  + (size_t)4 * D_ * D_;    // [D, 4D]
  short* xb   = qb2;                   // alias (used before Q GEMM)
  short* KVb  = LNb2;                  // alias (used before scale_ln)

  // ---- prep: weights to bf16 [N,K], x_m to bf16, concat K/V bias
  cvt_k<<<(M_ * DIN_ + 255) / 256, 256, 0, stream>>>(x_m, xb, M_ * DIN_);
  concat2_k<<<4, 256, 0, stream>>>(bk, bv, bkv, D_);
  tconv_k<<<dim3(D_/32,    DIN_/32),  256, 0, stream>>>(W_in, WtIn, DIN_, D_);
  tconv_k<<<dim3(D_/32,    D_/32),    256, 0, stream>>>(Wq,   WtQ,  D_,   D_);
  tconv_k<<<dim3(D_/32,    D_/32),    256, 0, stream>>>(Wk,   WtKV, D_,   D_);
  tconv_k<<<dim3(D_/32,    D_/32),    256, 0, stream>>>(Wv,   WtKV + (size_t)D_*D_, D_, D_);
  tconv_k<<<dim3(D_/32,    D_/32),    256, 0, stream>>>(Wo,   WtO,  D_,   D_);
  tconv_k<<<dim3((4*D_)/32, D_/32),   256, 0, stream>>>(W1,   Wt1,  D_,   4*D_);
  tconv_k<<<dim3(D_/32,  (4*D_)/32),  256, 0, stream>>>(W2,   Wt2,  4*D_, D_);

  // X = x_m @ W_in + b_in           (384 blocks)
  gemm_bt_t<128,64,4,2><<<dim3(D_/64, M_/128), 256, 0, stream>>>(
      xb, WtIn, b_in, nullptr, X, M_, D_, DIN_, 0);
  // KVb = LN(X)
  ln_k<<<M_, 256, 0, stream>>>(X, ln_kv_g, ln_kv_b, KVb);
  // K|V projection, N=1024       (384 blocks)
  gemm_bt_t<128,128,4,4><<<dim3((2*D_)/128, M_/128), 256, 0, stream>>>(
      KVb, WtKV, bkv, nullptr, KVpb, M_, 2*D_, D_, 2);

  // ---- both streams batched over 2M rows
  scale_ln_k<<<M2_, 256, 0, stream>>>(X, A, ln_q_g, ln_q_b, Xk2, LNb2);
  gemm_bt_t<128,128,4,4><<<dim3(D_/128, M2_/128), 256, 0, stream>>>(
      LNb2, WtQ, bq, nullptr, qb2, M2_, D_, D_, 2);          // 384 blocks
  attn_mfma_k<<<dim3(T_/QT_, H_, B_*K_), 256, 0, stream>>>(qb2, KVpb, LNb2);
  gemm_bt_t<128,128,4,4><<<dim3(D_/128, M2_/128), 256, 0, stream>>>(
      LNb2, WtO, bo, Xk2, Xk2, M2_, D_, D_, 0);              // y, in place
  ln_k<<<M2_, 256, 0, stream>>>(Xk2, ln_f_g, ln_f_b, LNb2);
  gemm_bt_t<128,128,4,4><<<dim3((4*D_)/128, M2_/128), 256, 0, stream>>>(
      LNb2, Wt1, b1, nullptr, H1b, M2_, 4*D_, D_, 3);        // 1536 blocks
  gemm_bt_t<128,64,4,2><<<dim3(D_/64, M2_/128), 256, 0, stream>>>(
      H1b, Wt2, b2, nullptr, T2, M2_, D_, 4*D_, 0);          // 768 blocks
  final_ln_k<<<M2_, 256, 0, stream>>>(Xk2, T2, tags, ln_s_g, ln_s_b, out);
}

// Round 6
// 414.458 us; speedup vs baseline: 3.6896x; 1.0501x over previous
//
#include <hip/hip_runtime.h>
#include <hip/hip_bf16.h>
#include <math.h>

#define B_    4
#define T_    1536
#define DIN_  512
#define D_    512
#define K_    2
#define H_    8
#define BAND_ 24
#define DH_   64
#define M_    (B_*T_)      // 6144 rows
#define M2_   (2*M_)       // both streams batched
#define ALPHA_ 6.0f
#define BETA_  0.5f
#define EPS_   1e-5f

using bf8  = __attribute__((ext_vector_type(8))) short;   // 8 bf16 (4 VGPRs)
using f32x4 = __attribute__((ext_vector_type(4))) float;  // 4 fp32 acc

__device__ __forceinline__ void async_copy16(const void* g, void* l) {
  __builtin_amdgcn_global_load_lds(
      (const __attribute__((address_space(1))) unsigned int*)g,
      (__attribute__((address_space(3))) unsigned int*)l, 16, 0, 0);
}

__device__ __forceinline__ short f2bf(float v) {
  __hip_bfloat16 h = (__hip_bfloat16)v;
  return *(short*)&h;
}
__device__ __forceinline__ float bf2f(short s) {
  union { unsigned u; float f; } c;
  c.u = ((unsigned)(unsigned short)s) << 16;
  return c.f;
}
// XOR-swizzle of 16B chunks within each 64-element column block (bank-conflict fix)
__device__ __forceinline__ int swz64(int row, int col) {
  return (col & ~63) | ((((col >> 3) ^ row) & 7) << 3) | (col & 7);
}

// ---------------- bf16 MFMA GEMM: C = A[M,Kd] @ Bt[N,Kd]^T + bias (+res fp32) (+gelu)
// A and Bt are chunk-swizzled (swz64 per row). flags: 1=gelu, 2=bf16 out, 4=swizzled bf16 out.
template<int BM, int BN, int NI, int NJ>
__global__ __launch_bounds__(256) void gemm_bt_t(
    const short* __restrict__ A, const short* __restrict__ Bt,
    const float* __restrict__ bias, const float* __restrict__ res,
    void* __restrict__ Cout, int M, int N, int Kd, int flags) {
  __shared__ short lA[BM * 64];
  __shared__ short lB[BN * 64];
  const int tid  = threadIdx.x;
  const int wave = tid >> 6, lane = tid & 63;
  const int block_m = blockIdx.y * BM, block_n = blockIdx.x * BN;
  const int wm = (wave & 1) * (BM / 2), wn = (wave >> 1) * (BN / 2);
  const int l15 = lane & 15, quad = lane >> 4, l7 = lane & 7;
  f32x4 acc[NI][NJ] = {};

  for (int k0 = 0; k0 < Kd; k0 += 64) {
    __syncthreads();               // previous tile's LDS reads complete
#pragma unroll
    for (int i = 0; i < BM / 32; ++i) {
      const int cb = wave * (BM * 2) + i * 64;
      const int c  = cb + lane;                 // chunk of 8 bf16
      async_copy16(A + (size_t)(block_m + (c >> 3)) * Kd + k0 + (c & 7) * 8,
                   &lA[cb * 8]);
    }
#pragma unroll
    for (int i = 0; i < BN / 32; ++i) {
      const int cb = wave * (BN * 2) + i * 64;
      const int c  = cb + lane;
      async_copy16(Bt + (size_t)(block_n + (c >> 3)) * Kd + k0 + (c & 7) * 8,
                   &lB[cb * 8]);
    }
    __syncthreads();               // barrier drains vmcnt => LDS tiles ready
#pragma unroll
    for (int ks = 0; ks < 2; ++ks) {
      bf8 af[NI], bfr[NJ];
#pragma unroll
      for (int i = 0; i < NI; ++i)
        af[i] = *(const bf8*)&lA[(wm + i * 16 + l15) * 64 + (((ks * 4 + quad) ^ l7) << 3)];
#pragma unroll
      for (int j = 0; j < NJ; ++j)
        bfr[j] = *(const bf8*)&lB[(wn + j * 16 + l15) * 64 + (((ks * 4 + quad) ^ l7) << 3)];
#pragma unroll
      for (int i = 0; i < NI; ++i)
#pragma unroll
        for (int j = 0; j < NJ; ++j)
          acc[i][j] = __builtin_amdgcn_mfma_f32_16x16x32_bf16(af[i], bfr[j], acc[i][j], 0, 0, 0);
    }
  }

  const int do_gelu = flags & 1, out_bf = flags & 2, out_sw = flags & 4;
#pragma unroll
  for (int i = 0; i < NI; ++i) {
    const int mbase = block_m + wm + i * 16 + (lane >> 4) * 4;
#pragma unroll
    for (int j = 0; j < NJ; ++j) {
      const int col = block_n + wn + j * 16 + l15;
      const float bb = bias[col];
#pragma unroll
      for (int r = 0; r < 4; ++r) {
        const int row = mbase + r;
        float v = acc[i][j][r] + bb;
        if (res) v += res[(size_t)row * N + col];
        if (do_gelu) v = 0.5f * v * (1.0f + erff(v * 0.70710678118654752f));
        if (out_bf) {
          const int oc = out_sw ? swz64(row, col) : col;
          ((short*)Cout)[(size_t)row * N + oc] = f2bf(v);
        } else {
          ((float*)Cout)[(size_t)row * N + col] = v;
        }
      }
    }
  }
}

// ---------------- transpose + convert: W[K,N] fp32 -> Wt[N,K] bf16 (chunk-swizzled)
__global__ __launch_bounds__(256) void tconv_k(const float* __restrict__ W,
                                               short* __restrict__ Wt, int K, int N) {
  __shared__ float s[32][33];
  const int tx = threadIdx.x & 31, ty = threadIdx.x >> 5;  // ty 0..7
  const int k0 = blockIdx.y * 32, n0 = blockIdx.x * 32;
#pragma unroll
  for (int r = 0; r < 4; ++r)
    s[ty * 4 + r][tx] = W[(size_t)(k0 + ty * 4 + r) * N + n0 + tx];
  __syncthreads();
#pragma unroll
  for (int r = 0; r < 4; ++r) {
    const int n = n0 + ty * 4 + r;
    Wt[(size_t)n * K + swz64(n, k0 + tx)] = f2bf(s[tx][ty * 4 + r]);
  }
}

// ---------------- fp32 -> bf16 elementwise (chunk-swizzled, width 512)
__global__ void cvt_k(const float* __restrict__ x, short* __restrict__ y, int n) {
  const int i = blockIdx.x * blockDim.x + threadIdx.x;
  if (i < n) {
    const int row = i >> 9, col = i & 511;
    y[((size_t)row << 9) | swz64(row, col)] = f2bf(x[i]);
  }
}

// ---------------- concat two bias vectors [n]+[n] -> [2n]
__global__ void concat2_k(const float* __restrict__ a, const float* __restrict__ b,
                          float* __restrict__ o, int n) {
  const int i = blockIdx.x * blockDim.x + threadIdx.x;
  if (i < n) o[i] = a[i];
  else if (i < 2 * n) o[i] = b[i - n];
}

// ---------------- block reduction helper (256 threads)
__device__ __forceinline__ float block_sum(float s, float* red, int tid) {
  red[tid] = s; __syncthreads();
  for (int o = 128; o > 0; o >>= 1) {
    if (tid < o) red[tid] += red[tid + o];
    __syncthreads();
  }
  float r = red[0];
  __syncthreads();
  return r;
}

// ---------------- LayerNorm: out(bf16, swizzled) = LN(in) * g + b  (grid = rows)
__global__ __launch_bounds__(256) void ln_k(const float* __restrict__ in,
                                            const float* __restrict__ g,
                                            const float* __restrict__ b,
                                            short* __restrict__ out) {
  __shared__ float red[256];
  const int row = blockIdx.x, tid = threadIdx.x;
  const float* x = in + (size_t)row * D_;
  const float v0 = x[tid], v1 = x[tid + 256];
  const float mean = block_sum(v0 + v1, red, tid) * (1.0f / D_);
  const float d0 = v0 - mean, d1 = v1 - mean;
  const float var = block_sum(d0 * d0 + d1 * d1, red, tid) * (1.0f / D_);
  const float inv = rsqrtf(var + EPS_);
  out[(size_t)row * D_ + swz64(row, tid)]       = f2bf(d0 * inv * g[tid]       + b[tid]);
  out[(size_t)row * D_ + swz64(row, tid + 256)] = f2bf(d1 * inv * g[tid + 256] + b[tid + 256]);
}

// ---------------- gate + LN, both streams: grid = 2M rows (bf16 out swizzled)
__global__ __launch_bounds__(256) void scale_ln_k(
    const float* __restrict__ X, const float* __restrict__ Ain,
    const float* __restrict__ g, const float* __restrict__ b,
    float* __restrict__ Xk, short* __restrict__ out) {
  __shared__ float red[256];
  const int row = blockIdx.x, tid = threadIdx.x;
  const int kk = row / M_, rm = row % M_;
  const float a = Ain[(size_t)rm * K_ + kk];
  const float w = 1.0f / (1.0f + __expf(-ALPHA_ * (a - BETA_)));
  const float v0 = X[(size_t)rm * D_ + tid] * w;
  const float v1 = X[(size_t)rm * D_ + tid + 256] * w;
  Xk[(size_t)row * D_ + tid] = v0;
  Xk[(size_t)row * D_ + tid + 256] = v1;
  const float mean = block_sum(v0 + v1, red, tid) * (1.0f / D_);
  const float d0 = v0 - mean, d1 = v1 - mean;
  const float var = block_sum(d0 * d0 + d1 * d1, red, tid) * (1.0f / D_);
  const float inv = rsqrtf(var + EPS_);
  out[(size_t)row * D_ + swz64(row, tid)]       = f2bf(d0 * inv * g[tid]       + b[tid]);
  out[(size_t)row * D_ + swz64(row, tid + 256)] = f2bf(d1 * inv * g[tid + 256] + b[tid + 256]);
}

// ---------------- final LN, both streams: grid = 2M rows, scatter to concat layout
__global__ __launch_bounds__(256) void final_ln_k(
    const float* __restrict__ y, const float* __restrict__ h2,
    const float* __restrict__ tags,
    const float* __restrict__ g, const float* __restrict__ b,
    float* __restrict__ out) {
  __shared__ float red[256];
  const int row = blockIdx.x, tid = threadIdx.x;
  const int kk = row / M_, rm = row % M_;
  const int bb = rm / T_, t = rm % T_;
  const size_t orow = (size_t)bb * (K_ * T_) + (size_t)kk * T_ + t;
  const float v0 = y[(size_t)row * D_ + tid] + h2[(size_t)row * D_ + tid]
                 + tags[(size_t)kk * D_ + tid];
  const float v1 = y[(size_t)row * D_ + tid + 256] + h2[(size_t)row * D_ + tid + 256]
                 + tags[(size_t)kk * D_ + tid + 256];
  const float mean = block_sum(v0 + v1, red, tid) * (1.0f / D_);
  const float d0 = v0 - mean, d1 = v1 - mean;
  const float var = block_sum(d0 * d0 + d1 * d1, red, tid) * (1.0f / D_);
  const float inv = rsqrtf(var + EPS_);
  out[orow * D_ + tid]       = d0 * inv * g[tid]       + b[tid];
  out[orow * D_ + tid + 256] = d1 * inv * g[tid + 256] + b[tid + 256];
}

// ---------------- MFMA banded attention, both streams
// q [2M,D] bf16 (unswizzled); KVp [M,2D] bf16 (unswizzled); out bf16 swizzled
#define QT_  64
#define KT_  (QT_ + 2 * BAND_)   // 112 rows
#define SKQ_ 72                  // row stride (shorts) for sK/sQ/sP
#define STV_ 136                 // row stride (shorts) for sVt
__global__ __launch_bounds__(256) void attn_mfma_k(
    const short* __restrict__ q, const short* __restrict__ KVp,
    short* __restrict__ out) {
  __shared__ short sK[KT_ * SKQ_];
  __shared__ short sQ[QT_ * SKQ_];
  __shared__ short sVt[DH_ * STV_];     // transposed: [dim][key row]
  __shared__ short sP[4][16 * SKQ_];
  const int t0 = blockIdx.x * QT_;
  const int h  = blockIdx.y;
  const int z  = blockIdx.z;            // kk*B + b
  const int b  = z % B_;
  const int tid = threadIdx.x;
  const int wave = tid >> 6, lane = tid & 63;
  const int rr = tid >> 5, c2 = tid & 31;

  for (int r0 = 0; r0 < KT_; r0 += 8) {
    const int r = r0 + rr;
    const int s = t0 - BAND_ + r;
    short2 kv = {0, 0}, vv = {0, 0};
    if (s >= 0 && s < T_) {
      const size_t g = (size_t)(b * T_ + s) * (2 * D_) + h * DH_ + c2 * 2;
      kv = *(const short2*)&KVp[g];
      vv = *(const short2*)&KVp[g + D_];
    }
    *(short2*)&sK[r * SKQ_ + c2 * 2] = kv;
    sVt[(c2 * 2)     * STV_ + r] = vv.x;
    sVt[(c2 * 2 + 1) * STV_ + r] = vv.y;
  }
  for (int r0 = 0; r0 < QT_; r0 += 8) {
    const int r = r0 + rr;
    const size_t g = (size_t)(z * T_ + t0 + r) * D_ + h * DH_ + c2 * 2;
    *(short2*)&sQ[r * SKQ_ + c2 * 2] = *(const short2*)&q[g];
  }
  __syncthreads();

  const int qg  = wave * 16;            // query group base (also key window base)
  const int l15 = lane & 15, quad = lane >> 4;

  // ---- S = Q16x64 @ K64x64^T  (8 MFMAs)
  bf8 qa0 = *(const bf8*)&sQ[(qg + l15) * SKQ_ + quad * 8];
  bf8 qa1 = *(const bf8*)&sQ[(qg + l15) * SKQ_ + 32 + quad * 8];
  f32x4 acc[4];
#pragma unroll
  for (int j = 0; j < 4; ++j) {
    const bf8 kb0 = *(const bf8*)&sK[(qg + j * 16 + l15) * SKQ_ + quad * 8];
    const bf8 kb1 = *(const bf8*)&sK[(qg + j * 16 + l15) * SKQ_ + 32 + quad * 8];
    f32x4 z4 = {0.f, 0.f, 0.f, 0.f};
    acc[j] = __builtin_amdgcn_mfma_f32_16x16x32_bf16(qa0, kb0, z4, 0, 0, 0);
    acc[j] = __builtin_amdgcn_mfma_f32_16x16x32_bf16(qa1, kb1, acc[j], 0, 0, 0);
  }

  // ---- banded softmax on C-layout rows (row = quad*4+reg, col = j*16+l15)
#pragma unroll
  for (int reg = 0; reg < 4; ++reg) {
    const int i = quad * 4 + reg;       // query within group
    float sc[4];
    float mx = -1e30f;
#pragma unroll
    for (int j = 0; j < 4; ++j) {
      const int c = j * 16 + l15;       // key within 64-window
      const int s = t0 + qg - BAND_ + c;
      const int rel = c - i;            // in [0,48] when inside band
      const bool valid = (rel >= 0) && (rel <= 2 * BAND_) && (s >= 0) && (s < T_);
      sc[j] = valid ? acc[j][reg] * 0.125f : -1e30f;
      mx = fmaxf(mx, sc[j]);
    }
    for (int o = 1; o < 16; o <<= 1) mx = fmaxf(mx, __shfl_xor(mx, o));
    float p[4], se = 0.0f;
#pragma unroll
    for (int j = 0; j < 4; ++j) {
      p[j] = (sc[j] > -1e29f) ? __expf(sc[j] - mx) : 0.0f;
      se += p[j];
    }
    for (int o = 1; o < 16; o <<= 1) se += __shfl_xor(se, o);
    const float inv = 1.0f / se;
#pragma unroll
    for (int j = 0; j < 4; ++j)
      sP[wave][i * SKQ_ + j * 16 + l15] = f2bf(p[j] * inv);
  }

  // ---- O = P16x64 @ V64x64  (8 MFMAs; V from transposed LDS)
  const bf8 pa0 = *(const bf8*)&sP[wave][l15 * SKQ_ + quad * 8];
  const bf8 pa1 = *(const bf8*)&sP[wave][l15 * SKQ_ + 32 + quad * 8];
  f32x4 oacc[4] = {};
#pragma unroll
  for (int dt = 0; dt < 4; ++dt) {
    const bf8 vb0 = *(const bf8*)&sVt[(dt * 16 + l15) * STV_ + qg + quad * 8];
    const bf8 vb1 = *(const bf8*)&sVt[(dt * 16 + l15) * STV_ + qg + 32 + quad * 8];
    oacc[dt] = __builtin_amdgcn_mfma_f32_16x16x32_bf16(pa0, vb0, oacc[dt], 0, 0, 0);
    oacc[dt] = __builtin_amdgcn_mfma_f32_16x16x32_bf16(pa1, vb1, oacc[dt], 0, 0, 0);
  }
#pragma unroll
  for (int dt = 0; dt < 4; ++dt)
#pragma unroll
    for (int reg = 0; reg < 4; ++reg) {
      const int i = quad * 4 + reg;
      const int row = t0 + qg + i;           // row % 8 == i % 8
      const int col = h * DH_ + dt * 16 + l15;
      out[(size_t)(z * T_ + row) * D_ + swz64(row, col)] = f2bf(oacc[dt][reg]);
    }
}

extern "C" void kernel_launch(void* const* d_in, const int* in_sizes, int n_in,
                              void* d_out, int out_size, void* d_ws, size_t ws_size,
                              hipStream_t stream) {
  const float* x_m    = (const float*)d_in[0];
  const float* A      = (const float*)d_in[1];
  const float* W_in   = (const float*)d_in[2];
  const float* b_in   = (const float*)d_in[3];
  const float* ln_q_g = (const float*)d_in[4];
  const float* ln_q_b = (const float*)d_in[5];
  const float* ln_kv_g= (const float*)d_in[6];
  const float* ln_kv_b= (const float*)d_in[7];
  const float* Wq     = (const float*)d_in[8];
  const float* bq     = (const float*)d_in[9];
  const float* Wk     = (const float*)d_in[10];
  const float* bk     = (const float*)d_in[11];
  const float* Wv     = (const float*)d_in[12];
  const float* bv     = (const float*)d_in[13];
  const float* Wo     = (const float*)d_in[14];
  const float* bo     = (const float*)d_in[15];
  const float* ln_f_g = (const float*)d_in[16];
  const float* ln_f_b = (const float*)d_in[17];
  const float* W1     = (const float*)d_in[18];
  const float* b1     = (const float*)d_in[19];
  const float* W2     = (const float*)d_in[20];
  const float* b2     = (const float*)d_in[21];
  const float* ln_s_g = (const float*)d_in[22];
  const float* ln_s_b = (const float*)d_in[23];
  const float* tags   = (const float*)d_in[24];
  float* out = (float*)d_out;

  const size_t MD = (size_t)M_ * D_;
  // fp32 buffers
  float* X   = (float*)d_ws;           // [M,D]
  float* Xk2 = X   + MD;               // [2M,D]  gated X, then y (in place)
  float* T2  = Xk2 + 2 * MD;           // [2M,D]  W2 out
  float* bkv = T2  + 2 * MD;           // [1024]
  // bf16 buffers
  short* LNb2 = (short*)(bkv + 1024);  // [2M,D]; first MD also = KV LN
  short* qb2  = LNb2 + 2 * MD;         // [2M,D]; first MD also = xb (x_m bf16)
  short* KVpb = qb2  + 2 * MD;         // [M,2D] interleaved K|V (unswizzled)
  short* H1b  = KVpb + 2 * MD;         // [2M,4D]
  short* WtIn = H1b + (size_t)M2_ * 4 * D_;
  short* WtQ  = WtIn + (size_t)D_ * DIN_;
  short* WtKV = WtQ  + (size_t)D_ * D_;        // [2D, D]
  short* WtO  = WtKV + (size_t)2 * D_ * D_;
  short* Wt1  = WtO  + (size_t)D_ * D_;        // [4D, D]
  short* Wt2  = Wt1  + (size_t)4 * D_ * D_;    // [D, 4D]
  short* xb   = qb2;                   // alias (used before Q GEMM)
  short* KVb  = LNb2;                  // alias (used before scale_ln)

  // ---- prep: weights to bf16 [N,K] swizzled, x_m to bf16 swizzled, concat K/V bias
  cvt_k<<<(M_ * DIN_ + 255) / 256, 256, 0, stream>>>(x_m, xb, M_ * DIN_);
  concat2_k<<<4, 256, 0, stream>>>(bk, bv, bkv, D_);
  tconv_k<<<dim3(D_/32,    DIN_/32),  256, 0, stream>>>(W_in, WtIn, DIN_, D_);
  tconv_k<<<dim3(D_/32,    D_/32),    256, 0, stream>>>(Wq,   WtQ,  D_,   D_);
  tconv_k<<<dim3(D_/32,    D_/32),    256, 0, stream>>>(Wk,   WtKV, D_,   D_);
  tconv_k<<<dim3(D_/32,    D_/32),    256, 0, stream>>>(Wv,   WtKV + (size_t)D_*D_, D_, D_);
  tconv_k<<<dim3(D_/32,    D_/32),    256, 0, stream>>>(Wo,   WtO,  D_,   D_);
  tconv_k<<<dim3((4*D_)/32, D_/32),   256, 0, stream>>>(W1,   Wt1,  D_,   4*D_);
  tconv_k<<<dim3(D_/32,  (4*D_)/32),  256, 0, stream>>>(W2,   Wt2,  4*D_, D_);

  // X = x_m @ W_in + b_in           (384 blocks)
  gemm_bt_t<128,64,4,2><<<dim3(D_/64, M_/128), 256, 0, stream>>>(
      xb, WtIn, b_in, nullptr, X, M_, D_, DIN_, 0);
  // KVb = LN(X)  (swizzled bf16)
  ln_k<<<M_, 256, 0, stream>>>(X, ln_kv_g, ln_kv_b, KVb);
  // K|V projection, N=1024 (bf16 out, UNswizzled: consumed by attention)
  gemm_bt_t<128,128,4,4><<<dim3((2*D_)/128, M_/128), 256, 0, stream>>>(
      KVb, WtKV, bkv, nullptr, KVpb, M_, 2*D_, D_, 2);

  // ---- both streams batched over 2M rows
  scale_ln_k<<<M2_, 256, 0, stream>>>(X, A, ln_q_g, ln_q_b, Xk2, LNb2);
  gemm_bt_t<128,128,4,4><<<dim3(D_/128, M2_/128), 256, 0, stream>>>(
      LNb2, WtQ, bq, nullptr, qb2, M2_, D_, D_, 2);          // q: unswizzled
  attn_mfma_k<<<dim3(T_/QT_, H_, B_*K_), 256, 0, stream>>>(qb2, KVpb, LNb2);
  gemm_bt_t<128,128,4,4><<<dim3(D_/128, M2_/128), 256, 0, stream>>>(
      LNb2, WtO, bo, Xk2, Xk2, M2_, D_, D_, 0);              // y, in place
  ln_k<<<M2_, 256, 0, stream>>>(Xk2, ln_f_g, ln_f_b, LNb2);
  gemm_bt_t<128,128,4,4><<<dim3((4*D_)/128, M2_/128), 256, 0, stream>>>(
      LNb2, Wt1, b1, nullptr, H1b, M2_, 4*D_, D_, 7);        // gelu + bf16 swizzled
  gemm_bt_t<128,64,4,2><<<dim3(D_/64, M2_/128), 256, 0, stream>>>(
      H1b, Wt2, b2, nullptr, T2, M2_, D_, 4*D_, 0);          // 768 blocks
  final_ln_k<<<M2_, 256, 0, stream>>>(Xk2, T2, tags, ln_s_g, ln_s_b, out);
}

// Round 7
// 379.801 us; speedup vs baseline: 4.0263x; 1.0912x over previous
//
#include <hip/hip_runtime.h>
#include <hip/hip_bf16.h>
#include <math.h>

#define B_    4
#define T_    1536
#define DIN_  512
#define D_    512
#define K_    2
#define H_    8
#define BAND_ 24
#define DH_   64
#define M_    (B_*T_)      // 6144 rows
#define M2_   (2*M_)       // both streams batched
#define ALPHA_ 6.0f
#define BETA_  0.5f
#define EPS_   1e-5f

using bf8  = __attribute__((ext_vector_type(8))) short;   // 8 bf16 (4 VGPRs)
using f32x4 = __attribute__((ext_vector_type(4))) float;  // 4 fp32 acc

__device__ __forceinline__ void async_copy16(const void* g, void* l) {
  __builtin_amdgcn_global_load_lds(
      (const __attribute__((address_space(1))) unsigned int*)g,
      (__attribute__((address_space(3))) unsigned int*)l, 16, 0, 0);
}

__device__ __forceinline__ short f2bf(float v) {
  __hip_bfloat16 h = (__hip_bfloat16)v;
  return *(short*)&h;
}
__device__ __forceinline__ float bf2f(short s) {
  union { unsigned u; float f; } c;
  c.u = ((unsigned)(unsigned short)s) << 16;
  return c.f;
}
// XOR-swizzle of 16B chunks within each 64-element column block (bank-conflict fix)
__device__ __forceinline__ int swz64(int row, int col) {
  return (col & ~63) | ((((col >> 3) ^ row) & 7) << 3) | (col & 7);
}

// ---------------- bf16 MFMA GEMM: C = A[M,Kd] @ Bt[N,Kd]^T + bias (+res fp32) (+gelu)
// A and Bt are chunk-swizzled (swz64 per row). flags: 1=gelu, 2=bf16 out, 4=swizzled bf16 out.
// 1-D grid of gx*gy blocks; XCD-aware remap: blocks with id%8==x (XCD x) cover
// contiguous row-tiles with all gx column-tiles consecutive -> A-tile fetched
// by exactly one XCD's L2. Requires gy % 8 == 0.
template<int BM, int BN, int NI, int NJ>
__global__ __launch_bounds__(256) void gemm_bt_t(
    const short* __restrict__ A, const short* __restrict__ Bt,
    const float* __restrict__ bias, const float* __restrict__ res,
    void* __restrict__ Cout, int M, int N, int Kd, int flags, int gx) {
  __shared__ short lA[BM * 64];
  __shared__ short lB[BN * 64];
  const int gy   = gridDim.x / gx;
  const int xcd  = blockIdx.x & 7;
  const int seq  = blockIdx.x >> 3;
  const int rpx  = gy >> 3;                 // row-tiles per XCD
  const int by   = xcd * rpx + seq / gx;
  const int bx   = seq % gx;
  const int tid  = threadIdx.x;
  const int wave = tid >> 6, lane = tid & 63;
  const int block_m = by * BM, block_n = bx * BN;
  const int wm = (wave & 1) * (BM / 2), wn = (wave >> 1) * (BN / 2);
  const int l15 = lane & 15, quad = lane >> 4, l7 = lane & 7;
  f32x4 acc[NI][NJ] = {};

  for (int k0 = 0; k0 < Kd; k0 += 64) {
    __syncthreads();               // previous tile's LDS reads complete
#pragma unroll
    for (int i = 0; i < BM / 32; ++i) {
      const int cb = wave * (BM * 2) + i * 64;
      const int c  = cb + lane;                 // chunk of 8 bf16
      async_copy16(A + (size_t)(block_m + (c >> 3)) * Kd + k0 + (c & 7) * 8,
                   &lA[cb * 8]);
    }
#pragma unroll
    for (int i = 0; i < BN / 32; ++i) {
      const int cb = wave * (BN * 2) + i * 64;
      const int c  = cb + lane;
      async_copy16(Bt + (size_t)(block_n + (c >> 3)) * Kd + k0 + (c & 7) * 8,
                   &lB[cb * 8]);
    }
    __syncthreads();               // barrier drains vmcnt => LDS tiles ready
#pragma unroll
    for (int ks = 0; ks < 2; ++ks) {
      bf8 af[NI], bfr[NJ];
#pragma unroll
      for (int i = 0; i < NI; ++i)
        af[i] = *(const bf8*)&lA[(wm + i * 16 + l15) * 64 + (((ks * 4 + quad) ^ l7) << 3)];
#pragma unroll
      for (int j = 0; j < NJ; ++j)
        bfr[j] = *(const bf8*)&lB[(wn + j * 16 + l15) * 64 + (((ks * 4 + quad) ^ l7) << 3)];
#pragma unroll
      for (int i = 0; i < NI; ++i)
#pragma unroll
        for (int j = 0; j < NJ; ++j)
          acc[i][j] = __builtin_amdgcn_mfma_f32_16x16x32_bf16(af[i], bfr[j], acc[i][j], 0, 0, 0);
    }
  }

  const int do_gelu = flags & 1, out_bf = flags & 2, out_sw = flags & 4;
#pragma unroll
  for (int i = 0; i < NI; ++i) {
    const int mbase = block_m + wm + i * 16 + (lane >> 4) * 4;
#pragma unroll
    for (int j = 0; j < NJ; ++j) {
      const int col = block_n + wn + j * 16 + l15;
      const float bb = bias[col];
#pragma unroll
      for (int r = 0; r < 4; ++r) {
        const int row = mbase + r;
        float v = acc[i][j][r] + bb;
        if (res) v += res[(size_t)row * N + col];
        if (do_gelu) v = 0.5f * v * (1.0f + erff(v * 0.70710678118654752f));
        if (out_bf) {
          const int oc = out_sw ? swz64(row, col) : col;
          ((short*)Cout)[(size_t)row * N + oc] = f2bf(v);
        } else {
          ((float*)Cout)[(size_t)row * N + col] = v;
        }
      }
    }
  }
}

// ---------------- transpose + convert: W[K,N] fp32 -> Wt[N,K] bf16 (chunk-swizzled)
__global__ __launch_bounds__(256) void tconv_k(const float* __restrict__ W,
                                               short* __restrict__ Wt, int K, int N) {
  __shared__ float s[32][33];
  const int tx = threadIdx.x & 31, ty = threadIdx.x >> 5;  // ty 0..7
  const int k0 = blockIdx.y * 32, n0 = blockIdx.x * 32;
#pragma unroll
  for (int r = 0; r < 4; ++r)
    s[ty * 4 + r][tx] = W[(size_t)(k0 + ty * 4 + r) * N + n0 + tx];
  __syncthreads();
#pragma unroll
  for (int r = 0; r < 4; ++r) {
    const int n = n0 + ty * 4 + r;
    Wt[(size_t)n * K + swz64(n, k0 + tx)] = f2bf(s[tx][ty * 4 + r]);
  }
}

// ---------------- fp32 -> bf16 elementwise (chunk-swizzled, width 512)
__global__ void cvt_k(const float* __restrict__ x, short* __restrict__ y, int n) {
  const int i = blockIdx.x * blockDim.x + threadIdx.x;
  if (i < n) {
    const int row = i >> 9, col = i & 511;
    y[((size_t)row << 9) | swz64(row, col)] = f2bf(x[i]);
  }
}

// ---------------- concat two bias vectors [n]+[n] -> [2n]
__global__ void concat2_k(const float* __restrict__ a, const float* __restrict__ b,
                          float* __restrict__ o, int n) {
  const int i = blockIdx.x * blockDim.x + threadIdx.x;
  if (i < n) o[i] = a[i];
  else if (i < 2 * n) o[i] = b[i - n];
}

// ---------------- block reduction helper (256 threads)
__device__ __forceinline__ float block_sum(float s, float* red, int tid) {
  red[tid] = s; __syncthreads();
  for (int o = 128; o > 0; o >>= 1) {
    if (tid < o) red[tid] += red[tid + o];
    __syncthreads();
  }
  float r = red[0];
  __syncthreads();
  return r;
}

// ---------------- LayerNorm: out(bf16, swizzled) = LN(in) * g + b  (grid = rows)
__global__ __launch_bounds__(256) void ln_k(const float* __restrict__ in,
                                            const float* __restrict__ g,
                                            const float* __restrict__ b,
                                            short* __restrict__ out) {
  __shared__ float red[256];
  const int row = blockIdx.x, tid = threadIdx.x;
  const float* x = in + (size_t)row * D_;
  const float v0 = x[tid], v1 = x[tid + 256];
  const float mean = block_sum(v0 + v1, red, tid) * (1.0f / D_);
  const float d0 = v0 - mean, d1 = v1 - mean;
  const float var = block_sum(d0 * d0 + d1 * d1, red, tid) * (1.0f / D_);
  const float inv = rsqrtf(var + EPS_);
  out[(size_t)row * D_ + swz64(row, tid)]       = f2bf(d0 * inv * g[tid]       + b[tid]);
  out[(size_t)row * D_ + swz64(row, tid + 256)] = f2bf(d1 * inv * g[tid + 256] + b[tid + 256]);
}

// ---------------- gate + LN, both streams: grid = 2M rows (bf16 out swizzled)
__global__ __launch_bounds__(256) void scale_ln_k(
    const float* __restrict__ X, const float* __restrict__ Ain,
    const float* __restrict__ g, const float* __restrict__ b,
    float* __restrict__ Xk, short* __restrict__ out) {
  __shared__ float red[256];
  const int row = blockIdx.x, tid = threadIdx.x;
  const int kk = row / M_, rm = row % M_;
  const float a = Ain[(size_t)rm * K_ + kk];
  const float w = 1.0f / (1.0f + __expf(-ALPHA_ * (a - BETA_)));
  const float v0 = X[(size_t)rm * D_ + tid] * w;
  const float v1 = X[(size_t)rm * D_ + tid + 256] * w;
  Xk[(size_t)row * D_ + tid] = v0;
  Xk[(size_t)row * D_ + tid + 256] = v1;
  const float mean = block_sum(v0 + v1, red, tid) * (1.0f / D_);
  const float d0 = v0 - mean, d1 = v1 - mean;
  const float var = block_sum(d0 * d0 + d1 * d1, red, tid) * (1.0f / D_);
  const float inv = rsqrtf(var + EPS_);
  out[(size_t)row * D_ + swz64(row, tid)]       = f2bf(d0 * inv * g[tid]       + b[tid]);
  out[(size_t)row * D_ + swz64(row, tid + 256)] = f2bf(d1 * inv * g[tid + 256] + b[tid + 256]);
}

// ---------------- final LN, both streams: grid = 2M rows, scatter to concat layout
__global__ __launch_bounds__(256) void final_ln_k(
    const float* __restrict__ y, const float* __restrict__ h2,
    const float* __restrict__ tags,
    const float* __restrict__ g, const float* __restrict__ b,
    float* __restrict__ out) {
  __shared__ float red[256];
  const int row = blockIdx.x, tid = threadIdx.x;
  const int kk = row / M_, rm = row % M_;
  const int bb = rm / T_, t = rm % T_;
  const size_t orow = (size_t)bb * (K_ * T_) + (size_t)kk * T_ + t;
  const float v0 = y[(size_t)row * D_ + tid] + h2[(size_t)row * D_ + tid]
                 + tags[(size_t)kk * D_ + tid];
  const float v1 = y[(size_t)row * D_ + tid + 256] + h2[(size_t)row * D_ + tid + 256]
                 + tags[(size_t)kk * D_ + tid + 256];
  const float mean = block_sum(v0 + v1, red, tid) * (1.0f / D_);
  const float d0 = v0 - mean, d1 = v1 - mean;
  const float var = block_sum(d0 * d0 + d1 * d1, red, tid) * (1.0f / D_);
  const float inv = rsqrtf(var + EPS_);
  out[orow * D_ + tid]       = d0 * inv * g[tid]       + b[tid];
  out[orow * D_ + tid + 256] = d1 * inv * g[tid + 256] + b[tid + 256];
}

// ---------------- MFMA banded attention, both streams
// q [2M,D] bf16 (unswizzled); KVp [M,2D] bf16 (unswizzled); out bf16 swizzled
#define QT_  64
#define KT_  (QT_ + 2 * BAND_)   // 112 rows
#define SKQ_ 72                  // row stride (shorts) for sK/sQ/sP
#define STV_ 136                 // row stride (shorts) for sVt
__global__ __launch_bounds__(256) void attn_mfma_k(
    const short* __restrict__ q, const short* __restrict__ KVp,
    short* __restrict__ out) {
  __shared__ short sK[KT_ * SKQ_];
  __shared__ short sQ[QT_ * SKQ_];
  __shared__ short sVt[DH_ * STV_];     // transposed: [dim][key row]
  __shared__ short sP[4][16 * SKQ_];
  const int t0 = blockIdx.x * QT_;
  const int h  = blockIdx.y;
  const int z  = blockIdx.z;            // kk*B + b
  const int b  = z % B_;
  const int tid = threadIdx.x;
  const int wave = tid >> 6, lane = tid & 63;
  const int rr = tid >> 5, c2 = tid & 31;

  for (int r0 = 0; r0 < KT_; r0 += 8) {
    const int r = r0 + rr;
    const int s = t0 - BAND_ + r;
    short2 kv = {0, 0}, vv = {0, 0};
    if (s >= 0 && s < T_) {
      const size_t g = (size_t)(b * T_ + s) * (2 * D_) + h * DH_ + c2 * 2;
      kv = *(const short2*)&KVp[g];
      vv = *(const short2*)&KVp[g + D_];
    }
    *(short2*)&sK[r * SKQ_ + c2 * 2] = kv;
    sVt[(c2 * 2)     * STV_ + r] = vv.x;
    sVt[(c2 * 2 + 1) * STV_ + r] = vv.y;
  }
  for (int r0 = 0; r0 < QT_; r0 += 8) {
    const int r = r0 + rr;
    const size_t g = (size_t)(z * T_ + t0 + r) * D_ + h * DH_ + c2 * 2;
    *(short2*)&sQ[r * SKQ_ + c2 * 2] = *(const short2*)&q[g];
  }
  __syncthreads();

  const int qg  = wave * 16;            // query group base (also key window base)
  const int l15 = lane & 15, quad = lane >> 4;

  // ---- S = Q16x64 @ K64x64^T  (8 MFMAs)
  bf8 qa0 = *(const bf8*)&sQ[(qg + l15) * SKQ_ + quad * 8];
  bf8 qa1 = *(const bf8*)&sQ[(qg + l15) * SKQ_ + 32 + quad * 8];
  f32x4 acc[4];
#pragma unroll
  for (int j = 0; j < 4; ++j) {
    const bf8 kb0 = *(const bf8*)&sK[(qg + j * 16 + l15) * SKQ_ + quad * 8];
    const bf8 kb1 = *(const bf8*)&sK[(qg + j * 16 + l15) * SKQ_ + 32 + quad * 8];
    f32x4 z4 = {0.f, 0.f, 0.f, 0.f};
    acc[j] = __builtin_amdgcn_mfma_f32_16x16x32_bf16(qa0, kb0, z4, 0, 0, 0);
    acc[j] = __builtin_amdgcn_mfma_f32_16x16x32_bf16(qa1, kb1, acc[j], 0, 0, 0);
  }

  // ---- banded softmax on C-layout rows (row = quad*4+reg, col = j*16+l15)
#pragma unroll
  for (int reg = 0; reg < 4; ++reg) {
    const int i = quad * 4 + reg;       // query within group
    float sc[4];
    float mx = -1e30f;
#pragma unroll
    for (int j = 0; j < 4; ++j) {
      const int c = j * 16 + l15;       // key within 64-window
      const int s = t0 + qg - BAND_ + c;
      const int rel = c - i;            // in [0,48] when inside band
      const bool valid = (rel >= 0) && (rel <= 2 * BAND_) && (s >= 0) && (s < T_);
      sc[j] = valid ? acc[j][reg] * 0.125f : -1e30f;
      mx = fmaxf(mx, sc[j]);
    }
    for (int o = 1; o < 16; o <<= 1) mx = fmaxf(mx, __shfl_xor(mx, o));
    float p[4], se = 0.0f;
#pragma unroll
    for (int j = 0; j < 4; ++j) {
      p[j] = (sc[j] > -1e29f) ? __expf(sc[j] - mx) : 0.0f;
      se += p[j];
    }
    for (int o = 1; o < 16; o <<= 1) se += __shfl_xor(se, o);
    const float inv = 1.0f / se;
#pragma unroll
    for (int j = 0; j < 4; ++j)
      sP[wave][i * SKQ_ + j * 16 + l15] = f2bf(p[j] * inv);
  }

  // ---- O = P16x64 @ V64x64  (8 MFMAs; V from transposed LDS)
  const bf8 pa0 = *(const bf8*)&sP[wave][l15 * SKQ_ + quad * 8];
  const bf8 pa1 = *(const bf8*)&sP[wave][l15 * SKQ_ + 32 + quad * 8];
  f32x4 oacc[4] = {};
#pragma unroll
  for (int dt = 0; dt < 4; ++dt) {
    const bf8 vb0 = *(const bf8*)&sVt[(dt * 16 + l15) * STV_ + qg + quad * 8];
    const bf8 vb1 = *(const bf8*)&sVt[(dt * 16 + l15) * STV_ + qg + 32 + quad * 8];
    oacc[dt] = __builtin_amdgcn_mfma_f32_16x16x32_bf16(pa0, vb0, oacc[dt], 0, 0, 0);
    oacc[dt] = __builtin_amdgcn_mfma_f32_16x16x32_bf16(pa1, vb1, oacc[dt], 0, 0, 0);
  }
#pragma unroll
  for (int dt = 0; dt < 4; ++dt)
#pragma unroll
    for (int reg = 0; reg < 4; ++reg) {
      const int i = quad * 4 + reg;
      const int row = t0 + qg + i;
      const int col = h * DH_ + dt * 16 + l15;
      out[(size_t)(z * T_ + row) * D_ + swz64(row, col)] = f2bf(oacc[dt][reg]);
    }
}

extern "C" void kernel_launch(void* const* d_in, const int* in_sizes, int n_in,
                              void* d_out, int out_size, void* d_ws, size_t ws_size,
                              hipStream_t stream) {
  const float* x_m    = (const float*)d_in[0];
  const float* A      = (const float*)d_in[1];
  const float* W_in   = (const float*)d_in[2];
  const float* b_in   = (const float*)d_in[3];
  const float* ln_q_g = (const float*)d_in[4];
  const float* ln_q_b = (const float*)d_in[5];
  const float* ln_kv_g= (const float*)d_in[6];
  const float* ln_kv_b= (const float*)d_in[7];
  const float* Wq     = (const float*)d_in[8];
  const float* bq     = (const float*)d_in[9];
  const float* Wk     = (const float*)d_in[10];
  const float* bk     = (const float*)d_in[11];
  const float* Wv     = (const float*)d_in[12];
  const float* bv     = (const float*)d_in[13];
  const float* Wo     = (const float*)d_in[14];
  const float* bo     = (const float*)d_in[15];
  const float* ln_f_g = (const float*)d_in[16];
  const float* ln_f_b = (const float*)d_in[17];
  const float* W1     = (const float*)d_in[18];
  const float* b1     = (const float*)d_in[19];
  const float* W2     = (const float*)d_in[20];
  const float* b2     = (const float*)d_in[21];
  const float* ln_s_g = (const float*)d_in[22];
  const float* ln_s_b = (const float*)d_in[23];
  const float* tags   = (const float*)d_in[24];
  float* out = (float*)d_out;

  const size_t MD = (size_t)M_ * D_;
  // fp32 buffers
  float* X   = (float*)d_ws;           // [M,D]
  float* Xk2 = X   + MD;               // [2M,D]  gated X, then y (in place)
  float* T2  = Xk2 + 2 * MD;           // [2M,D]  W2 out
  float* bkv = T2  + 2 * MD;           // [1024]
  // bf16 buffers
  short* LNb2 = (short*)(bkv + 1024);  // [2M,D]; first MD also = KV LN
  short* qb2  = LNb2 + 2 * MD;         // [2M,D]; first MD also = xb (x_m bf16)
  short* KVpb = qb2  + 2 * MD;         // [M,2D] interleaved K|V (unswizzled)
  short* H1b  = KVpb + 2 * MD;         // [2M,4D]
  short* WtIn = H1b + (size_t)M2_ * 4 * D_;
  short* WtQ  = WtIn + (size_t)D_ * DIN_;
  short* WtKV = WtQ  + (size_t)D_ * D_;        // [2D, D]
  short* WtO  = WtKV + (size_t)2 * D_ * D_;
  short* Wt1  = WtO  + (size_t)D_ * D_;        // [4D, D]
  short* Wt2  = Wt1  + (size_t)4 * D_ * D_;    // [D, 4D]
  short* xb   = qb2;                   // alias (used before Q GEMM)
  short* KVb  = LNb2;                  // alias (used before scale_ln)

  // ---- prep: weights to bf16 [N,K] swizzled, x_m to bf16 swizzled, concat K/V bias
  cvt_k<<<(M_ * DIN_ + 255) / 256, 256, 0, stream>>>(x_m, xb, M_ * DIN_);
  concat2_k<<<4, 256, 0, stream>>>(bk, bv, bkv, D_);
  tconv_k<<<dim3(D_/32,    DIN_/32),  256, 0, stream>>>(W_in, WtIn, DIN_, D_);
  tconv_k<<<dim3(D_/32,    D_/32),    256, 0, stream>>>(Wq,   WtQ,  D_,   D_);
  tconv_k<<<dim3(D_/32,    D_/32),    256, 0, stream>>>(Wk,   WtKV, D_,   D_);
  tconv_k<<<dim3(D_/32,    D_/32),    256, 0, stream>>>(Wv,   WtKV + (size_t)D_*D_, D_, D_);
  tconv_k<<<dim3(D_/32,    D_/32),    256, 0, stream>>>(Wo,   WtO,  D_,   D_);
  tconv_k<<<dim3((4*D_)/32, D_/32),   256, 0, stream>>>(W1,   Wt1,  D_,   4*D_);
  tconv_k<<<dim3(D_/32,  (4*D_)/32),  256, 0, stream>>>(W2,   Wt2,  4*D_, D_);

  // X = x_m @ W_in + b_in      (gx=8, gy=48 -> 384 blocks)
  gemm_bt_t<128,64,4,2><<<(D_/64) * (M_/128), 256, 0, stream>>>(
      xb, WtIn, b_in, nullptr, X, M_, D_, DIN_, 0, D_/64);
  // KVb = LN(X)  (swizzled bf16)
  ln_k<<<M_, 256, 0, stream>>>(X, ln_kv_g, ln_kv_b, KVb);
  // K|V projection, N=1024 (bf16 out, UNswizzled: consumed by attention)
  gemm_bt_t<128,128,4,4><<<((2*D_)/128) * (M_/128), 256, 0, stream>>>(
      KVb, WtKV, bkv, nullptr, KVpb, M_, 2*D_, D_, 2, (2*D_)/128);

  // ---- both streams batched over 2M rows
  scale_ln_k<<<M2_, 256, 0, stream>>>(X, A, ln_q_g, ln_q_b, Xk2, LNb2);
  gemm_bt_t<128,128,4,4><<<(D_/128) * (M2_/128), 256, 0, stream>>>(
      LNb2, WtQ, bq, nullptr, qb2, M2_, D_, D_, 2, D_/128);  // q: unswizzled
  attn_mfma_k<<<dim3(T_/QT_, H_, B_*K_), 256, 0, stream>>>(qb2, KVpb, LNb2);
  gemm_bt_t<128,128,4,4><<<(D_/128) * (M2_/128), 256, 0, stream>>>(
      LNb2, WtO, bo, Xk2, Xk2, M2_, D_, D_, 0, D_/128);      // y, in place
  ln_k<<<M2_, 256, 0, stream>>>(Xk2, ln_f_g, ln_f_b, LNb2);
  gemm_bt_t<128,128,4,4><<<((4*D_)/128) * (M2_/128), 256, 0, stream>>>(
      LNb2, Wt1, b1, nullptr, H1b, M2_, 4*D_, D_, 7, (4*D_)/128);  // gelu + bf16 swz
  gemm_bt_t<128,64,4,2><<<(D_/64) * (M2_/128), 256, 0, stream>>>(
      H1b, Wt2, b2, nullptr, T2, M2_, D_, 4*D_, 0, D_/64);   // 768 blocks
  final_ln_k<<<M2_, 256, 0, stream>>>(Xk2, T2, tags, ln_s_g, ln_s_b, out);
}